// Round 20
// baseline (360.936 us; speedup 1.0000x reference)
//
#include <hip/hip_runtime.h>
#include <hip/hip_bf16.h>

#define N_NODES 6144
#define MASK_WORDS 192  // 6144/32
#define LOG2E 1.44269504088896f

using short8 = __attribute__((ext_vector_type(8))) short;
using s16x4  = __attribute__((ext_vector_type(4))) short;
using f32x4  = __attribute__((ext_vector_type(4))) float;
using half2v = __attribute__((ext_vector_type(2))) _Float16;
using half8v = __attribute__((ext_vector_type(8))) _Float16;
struct Half2x4 { half2v v[4]; };

// f32 -> bf16 bits, round-to-nearest-even
__device__ inline unsigned f2bf_u(float f) {
  unsigned u = __builtin_bit_cast(unsigned, f);
  u += 0x7fff + ((u >> 16) & 1);
  return u >> 16;
}
__device__ inline short f2bf(float f) { return (short)f2bf_u(f); }

// async global->LDS, 16B per lane; lds base must be wave-uniform
__device__ inline void glds16(const short* g, short* l) {
  __builtin_amdgcn_global_load_lds(
      (const __attribute__((address_space(1))) unsigned int*)g,
      (__attribute__((address_space(3))) unsigned int*)l, 16, 0, 0);
}

// ---------------------------------------------------------------- bitpack
__global__ __launch_bounds__(256) void bitpack_kernel(const int* __restrict__ adj,
                                                      unsigned int* __restrict__ bits) {
  int row = blockIdx.x;
  int wave = threadIdx.x >> 6, lane = threadIdx.x & 63;
  const int* p = adj + (long)row * N_NODES;
  for (int base = wave * 64; base < N_NODES; base += 256) {
    unsigned long long m = __ballot(p[base + lane] > 0);
    if (lane == 0) {
      bits[row * MASK_WORDS + (base >> 5)] = (unsigned int)m;
      bits[row * MASK_WORDS + (base >> 5) + 1] = (unsigned int)(m >> 32);
    }
  }
}

// ---------------------------------------------------------------- W repack
__global__ __launch_bounds__(256) void repack_W_kernel(const float* __restrict__ W,
                                                       float* __restrict__ B,
                                                       int H, int Fin, int Fp) {
  int idx = blockIdx.x * blockDim.x + threadIdx.x;
  int total = H * Fin * Fp;
  if (idx >= total) return;
  int h = idx / (Fin * Fp);
  int rem = idx - h * (Fin * Fp);
  int k = rem / Fp, c = rem - k * Fp;
  B[k * (H * Fp) + h * Fp + c] = W[idx];
}

// ---------------------------------------------------------------- weight transpose+cvt (bf16)
__global__ __launch_bounds__(256) void transpose_w_kernel(const float* __restrict__ B,
                                                          short* __restrict__ Bt,
                                                          int K, int Nc) {
  __shared__ short t[32][33];
  int k0 = blockIdx.x * 32, c0 = blockIdx.y * 32;
  int tx = threadIdx.x & 31, ty = threadIdx.x >> 5;
  for (int r = ty; r < 32; r += 8) {
    float v = (c0 + tx < Nc) ? B[(size_t)(k0 + r) * Nc + c0 + tx] : 0.0f;
    t[tx][r] = f2bf(v);
  }
  __syncthreads();
  for (int r = ty; r < 32; r += 8)
    Bt[(size_t)(c0 + r) * K + k0 + tx] = t[r][tx];
}

// ---------------------------------------------------------------- MFMA GEMM (final linear only)
__global__ __launch_bounds__(256) void gemm_mfma_kernel(const float* __restrict__ A,
                                                        const short* __restrict__ Bt,
                                                        float* __restrict__ C,
                                                        int K, int Nc,
                                                        const float* __restrict__ bias,
                                                        int act) {
  __shared__ short As[64][40];
  __shared__ short Bs[64][40];
  int m0 = blockIdx.y * 64, n0 = blockIdx.x * 64;
  int tid = threadIdx.x;
  int w = tid >> 6, l = tid & 63, row_l = l & 15, grp = l >> 4;

  f32x4 acc[4] = {f32x4{0,0,0,0}, f32x4{0,0,0,0}, f32x4{0,0,0,0}, f32x4{0,0,0,0}};

  for (int k0 = 0; k0 < K; k0 += 32) {
    __syncthreads();
#pragma unroll
    for (int s = 0; s < 2; ++s) {
      int idx = tid + s * 256;
      int r = idx >> 3, q = idx & 7;
      float4 v = *reinterpret_cast<const float4*>(&A[(size_t)(m0 + r) * K + k0 + q * 4]);
      s16x4 sv = {f2bf(v.x), f2bf(v.y), f2bf(v.z), f2bf(v.w)};
      *reinterpret_cast<s16x4*>(&As[r][q * 4]) = sv;
    }
    {
      int c = tid >> 2, kq = tid & 3;
      *reinterpret_cast<short8*>(&Bs[c][kq * 8]) =
          *reinterpret_cast<const short8*>(&Bt[(size_t)(n0 + c) * K + k0 + kq * 8]);
    }
    __syncthreads();
    short8 a = *reinterpret_cast<const short8*>(&As[w * 16 + row_l][grp * 8]);
#pragma unroll
    for (int n = 0; n < 4; ++n) {
      short8 b = *reinterpret_cast<const short8*>(&Bs[n * 16 + row_l][grp * 8]);
      acc[n] = __builtin_amdgcn_mfma_f32_16x16x32_bf16(a, b, acc[n], 0, 0, 0);
    }
  }

#pragma unroll
  for (int n = 0; n < 4; ++n) {
#pragma unroll
    for (int k = 0; k < 4; ++k) {
      int row = m0 + w * 16 + grp * 4 + k;
      int col = n0 + n * 16 + row_l;
      if (col < Nc) {
        float v = acc[n][k];
        if (bias) v += bias[col];
        if (act == 1) v = fmaxf(v, 0.0f);
        C[(size_t)row * Nc + col] = v;
      }
    }
  }
}

// ---------------------------------------------------------------- attention GEMM (fused epilogue)
template<int HPB>
__global__ __launch_bounds__(256)
void gemm_attn_kernel(const float* __restrict__ A,
                      const short* __restrict__ Bt,
                      const float* __restrict__ avec,
                      short* __restrict__ WhT,
                      float* __restrict__ f1,
                      float* __restrict__ f2,
                      int K, int Nc, int Fp) {
  __shared__ short As[64][40];
  __shared__ short Bs[64][40];
  int m0 = blockIdx.y * 64, n0 = blockIdx.x * 64;
  int tid = threadIdx.x;
  int w = tid >> 6, l = tid & 63, row_l = l & 15, grp = l >> 4;

  f32x4 acc[4] = {f32x4{0,0,0,0}, f32x4{0,0,0,0}, f32x4{0,0,0,0}, f32x4{0,0,0,0}};

  for (int k0 = 0; k0 < K; k0 += 32) {
    __syncthreads();
#pragma unroll
    for (int s = 0; s < 2; ++s) {
      int idx = tid + s * 256;
      int r = idx >> 3, q = idx & 7;
      float4 v = *reinterpret_cast<const float4*>(&A[(size_t)(m0 + r) * K + k0 + q * 4]);
      s16x4 sv = {f2bf(v.x), f2bf(v.y), f2bf(v.z), f2bf(v.w)};
      *reinterpret_cast<s16x4*>(&As[r][q * 4]) = sv;
    }
    {
      int c = tid >> 2, kq = tid & 3;
      *reinterpret_cast<short8*>(&Bs[c][kq * 8]) =
          *reinterpret_cast<const short8*>(&Bt[(size_t)(n0 + c) * K + k0 + kq * 8]);
    }
    __syncthreads();
    short8 a = *reinterpret_cast<const short8*>(&As[w * 16 + row_l][grp * 8]);
#pragma unroll
    for (int n = 0; n < 4; ++n) {
      short8 b = *reinterpret_cast<const short8*>(&Bs[n * 16 + row_l][grp * 8]);
      acc[n] = __builtin_amdgcn_mfma_f32_16x16x32_bf16(a, b, acc[n], 0, 0, 0);
    }
  }

  int baserow = m0 + w * 16 + grp * 4;

#pragma unroll
  for (int n = 0; n < 4; ++n) {
    int col = n0 + n * 16 + row_l;
    _Float16 hv[4];
#pragma unroll
    for (int k = 0; k < 4; ++k) hv[k] = (_Float16)acc[n][k];
    *reinterpret_cast<s16x4*>(&WhT[(size_t)col * N_NODES + baserow]) =
        *reinterpret_cast<s16x4*>(hv);
  }

  constexpr int NPH = 4 / HPB;
#pragma unroll
  for (int half = 0; half < HPB; ++half) {
    int col0 = n0 + half * NPH * 16;
    int h = col0 / Fp;
    float t1[4] = {0, 0, 0, 0}, t2[4] = {0, 0, 0, 0};
#pragma unroll
    for (int nn = 0; nn < NPH; ++nn) {
      int n = half * NPH + nn;
      int col = n0 + n * 16 + row_l;
      int ci = col - h * Fp;
      float av1 = avec[h * 2 * Fp + ci] * LOG2E;
      float av2 = avec[h * 2 * Fp + Fp + ci] * LOG2E;
#pragma unroll
      for (int k = 0; k < 4; ++k) {
        t1[k] += acc[n][k] * av1;
        t2[k] += acc[n][k] * av2;
      }
    }
#pragma unroll
    for (int off = 1; off < 16; off <<= 1) {
#pragma unroll
      for (int k = 0; k < 4; ++k) {
        t1[k] += __shfl_xor(t1[k], off);
        t2[k] += __shfl_xor(t2[k], off);
      }
    }
    if (row_l == 0) {
#pragma unroll
      for (int k = 0; k < 4; ++k) {
        atomicAdd(&f1[h * N_NODES + baserow + k], t1[k]);
        atomicAdd(&f2[h * N_NODES + baserow + k], t2[k]);
      }
    }
  }
}

// ---------------------------------------------------------------- per-head global max of f2
__global__ __launch_bounds__(256) void gmax_kernel(const float* __restrict__ f2s,
                                                   float* __restrict__ gmax) {
  __shared__ float red[4];
  int h = blockIdx.x;
  int tid = threadIdx.x, lane = tid & 63, w = tid >> 6;
  const float* p = f2s + h * N_NODES;
  float m = -3.0e38f;
  for (int j = tid; j < N_NODES; j += 256) m = fmaxf(m, p[j]);
  for (int off = 32; off > 0; off >>= 1) m = fmaxf(m, __shfl_xor(m, off));
  if (lane == 0) red[w] = m;
  __syncthreads();
  if (tid == 0) gmax[h] = fmaxf(fmaxf(red[0], red[1]), fmaxf(red[2], red[3]));
}

// ---------------------------------------------------------------- attention PV (fp16, MI=2)
// 512 threads = 8 waves; each wave owns TWO 16-row strips (256 rows/block).
// Key: V fragment b8 is row-strip independent -> one ds_read feeds 2 MFMAs.
// Per-work, this halves V staging, barriers, and V LDS reads vs R18.
// P = max(Ai'E'_j, Bi'F'_j) & Mlut[wb] (fp16); 64-j stages, triple-buffered glds.
template<int NF, int JC>
__global__ __launch_bounds__(512)
void pv_stage_kernel(const float* __restrict__ f1s,
                     const float* __restrict__ f2s,
                     const float* __restrict__ gmax,
                     const unsigned int* __restrict__ bits,
                     const short* __restrict__ WhT,
                     float* __restrict__ pbuf,
                     float* __restrict__ lsum,
                     int H, int Fp) {
  constexpr int CH = N_NODES / JC;
  constexpr int COLS = NF * 16;
  constexpr int NS = CH / 64;
  constexpr int CHUNKS = COLS * 8;           // 16B chunks per stage buffer
  constexpr int NITER = (CHUNKS + 511) / 512;
  constexpr int STEP = COLS * 64;            // shorts per buffer
  constexpr int NCH = CH / 384;
  static_assert(NCH * 384 == CH, "chunking");

  __shared__ _Float16 Esh[CH];
  __shared__ _Float16 Fsh[CH];
  __shared__ short Vt[3 * STEP];
  __shared__ uint4 Mlut[256];

  int h = blockIdx.z;
  int cb0 = blockIdx.x * COLS;
  int rb = blockIdx.y % 24;
  int jc = blockIdx.y / 24;
  int i0 = rb * 256;
  int hN = h * N_NODES, hFp = h * Fp;
  int Ftot = H * Fp;
  int tid = threadIdx.x;
  int w = tid >> 6, l = tid & 63;
  int row_l = l & 15, grp = l >> 4;

  int vcol = hFp + cb0;
  const short* Wbase = WhT + (size_t)vcol * N_NODES;
  float gm = gmax[h];

  // ---- prologue: E/F from f2, mask LUT
  {
    const float4* srcF2 = reinterpret_cast<const float4*>(f2s + hN + jc * CH);
    for (int idx = tid; idx < CH / 4; idx += 512) {
      float4 v = srcF2[idx];
      float vv[4] = {v.x, v.y, v.z, v.w};
      _Float16 e4[4], f4[4];
#pragma unroll
      for (int q = 0; q < 4; ++q) {
        float d = vv[q] - gm;
        e4[q] = (_Float16)exp2f(d);
        f4[q] = (_Float16)exp2f(0.2f * d);
      }
      *reinterpret_cast<s16x4*>(&Esh[idx * 4]) = *reinterpret_cast<s16x4*>(e4);
      *reinterpret_cast<s16x4*>(&Fsh[idx * 4]) = *reinterpret_cast<s16x4*>(f4);
    }
    if (tid < 256) {
      unsigned v = tid;
      unsigned w0 = ((v & 1u) ? 0xFFFFu : 0u) | ((v & 2u) ? 0xFFFF0000u : 0u);
      unsigned w1 = ((v & 4u) ? 0xFFFFu : 0u) | ((v & 8u) ? 0xFFFF0000u : 0u);
      unsigned w2 = ((v & 16u) ? 0xFFFFu : 0u) | ((v & 32u) ? 0xFFFF0000u : 0u);
      unsigned w3 = ((v & 64u) ? 0xFFFFu : 0u) | ((v & 128u) ? 0xFFFF0000u : 0u);
      Mlut[v] = make_uint4(w0, w1, w2, w3);
    }
  }
  __syncthreads();

  // pre-swizzled per-lane global offsets per glds iter
  size_t goff[NITER];
#pragma unroll
  for (int it = 0; it < NITER; ++it) {
    int idx = tid + it * 512;
    int c = idx >> 3, sl = idx & 7;
    int slp = sl ^ (c & 7);
    goff[it] = (size_t)(c < COLS ? c : 0) * N_NODES + jc * CH + slp * 8;
  }

  auto issue = [&](int bsel, int j0) {
#pragma unroll
    for (int it = 0; it < NITER; ++it) {
      if (it * 512 + w * 64 < CHUNKS) {
        const short* g = Wbase + goff[it] + j0;
        short* lp = &Vt[bsel * STEP + it * 4096 + w * 512];
        glds16(g, lp);
      }
    }
  };

  issue(0, 0);
  if (NS > 1) issue(1, 64);

  // per-strip row state (MI=2)
  float fiA[2], Ahf[2], Bhf[2];
  const unsigned int* mbase[2];
#pragma unroll
  for (int mi = 0; mi < 2; ++mi) {
    int i = i0 + (mi * 8 + w) * 16 + row_l;
    float fi = f1s[hN + i];
    float m2 = fmaxf(fi + gm, 0.2f * (fi + gm));
    Ahf[mi] = exp2f(fi + gm - m2);
    Bhf[mi] = exp2f(0.2f * (fi + gm) - m2);
    mbase[mi] = bits + (size_t)i * MASK_WORDS + jc * (CH / 32);
    (void)fiA;
  }

  half8v ones8;
#pragma unroll
  for (int q = 0; q < 8; ++q) ones8[q] = (_Float16)1.0f;
  bool needL = (blockIdx.x == 0);

  f32x4 acc[2][NF];
#pragma unroll
  for (int mi = 0; mi < 2; ++mi)
#pragma unroll
    for (int n = 0; n < NF; ++n) acc[mi][n] = f32x4{0, 0, 0, 0};
  f32x4 accl[2] = {f32x4{0, 0, 0, 0}, f32x4{0, 0, 0, 0}};

  int scount = 0;
#pragma unroll 1
  for (int ch = 0; ch < NCH; ++ch) {
    unsigned mw[2][12];
#pragma unroll
    for (int mi = 0; mi < 2; ++mi) {
      const uint4* mp = reinterpret_cast<const uint4*>(mbase[mi] + ch * 12);
#pragma unroll
      for (int q = 0; q < 3; ++q) {
        uint4 m = mp[q];
        mw[mi][q * 4 + 0] = m.x; mw[mi][q * 4 + 1] = m.y;
        mw[mi][q * 4 + 2] = m.z; mw[mi][q * 4 + 3] = m.w;
      }
    }
#pragma unroll 1
    for (int s2 = 0; s2 < 6; ++s2) {
      if (scount + 1 == NS) {
        asm volatile("s_waitcnt vmcnt(0)" ::: "memory");
      } else if (NITER == 1) {
        asm volatile("s_waitcnt vmcnt(1)" ::: "memory");
      } else {
        asm volatile("s_waitcnt vmcnt(2)" ::: "memory");
      }
      __builtin_amdgcn_sched_barrier(0);
      __builtin_amdgcn_s_barrier();
      if (scount + 2 < NS) issue((scount + 2) % 3, (scount + 2) * 64);
      const short* vb = &Vt[(scount % 3) * STEP];
#pragma unroll
      for (int hh = 0; hh < 2; ++hh) {
        int jrel = scount * 64 + hh * 32 + grp * 8;
        half8v e8 = *reinterpret_cast<const half8v*>(&Esh[jrel]);
        half8v f8 = *reinterpret_cast<const half8v*>(&Fsh[jrel]);
        Half2x4 E2 = __builtin_bit_cast(Half2x4, e8);
        Half2x4 F2 = __builtin_bit_cast(Half2x4, f8);
        half8v a8[2];
#pragma unroll
        for (int mi = 0; mi < 2; ++mi) {
          unsigned wb = (mw[mi][s2 * 2 + hh] >> (grp * 8)) & 0xffu;
          uint4 mq4 = Mlut[wb];
          unsigned mka[4] = {mq4.x, mq4.y, mq4.z, mq4.w};
          half2v Ai2 = {(_Float16)Ahf[mi], (_Float16)Ahf[mi]};
          half2v Bi2 = {(_Float16)Bhf[mi], (_Float16)Bhf[mi]};
          Half2x4 P2;
#pragma unroll
          for (int ep = 0; ep < 4; ++ep) {
            half2v p2 = __builtin_elementwise_max(Ai2 * E2.v[ep], Bi2 * F2.v[ep]);
            unsigned pm = __builtin_bit_cast(unsigned, p2) & mka[ep];
            P2.v[ep] = __builtin_bit_cast(half2v, pm);
          }
          a8[mi] = __builtin_bit_cast(half8v, P2);
        }
        int j8s = ((hh << 2) | grp) ^ (row_l & 7);
#pragma unroll
        for (int n = 0; n < NF; ++n) {
          short8 braw = *reinterpret_cast<const short8*>(&vb[(n * 16 + row_l) * 64 + j8s * 8]);
          half8v b8 = __builtin_bit_cast(half8v, braw);
          acc[0][n] = __builtin_amdgcn_mfma_f32_16x16x32_f16(a8[0], b8, acc[0][n], 0, 0, 0);
          acc[1][n] = __builtin_amdgcn_mfma_f32_16x16x32_f16(a8[1], b8, acc[1][n], 0, 0, 0);
        }
        if (needL) {
          accl[0] = __builtin_amdgcn_mfma_f32_16x16x32_f16(a8[0], ones8, accl[0], 0, 0, 0);
          accl[1] = __builtin_amdgcn_mfma_f32_16x16x32_f16(a8[1], ones8, accl[1], 0, 0, 0);
        }
      }
      ++scount;
    }
  }

  float* outp = pbuf + (size_t)jc * N_NODES * Ftot;
#pragma unroll
  for (int mi = 0; mi < 2; ++mi) {
#pragma unroll
    for (int n = 0; n < NF; ++n) {
#pragma unroll
      for (int k = 0; k < 4; ++k) {
        int r = i0 + (mi * 8 + w) * 16 + grp * 4 + k;
        outp[(size_t)r * Ftot + vcol + n * 16 + row_l] = acc[mi][n][k];
      }
    }
    if (needL && row_l == 0) {
#pragma unroll
      for (int k = 0; k < 4; ++k)
        atomicAdd(&lsum[hN + i0 + (mi * 8 + w) * 16 + grp * 4 + k], accl[mi][k]);
    }
  }
}

// ---------------------------------------------------------------- reduce + activation
__global__ __launch_bounds__(256) void act_kernel(float* __restrict__ dst,
                                                  const float* __restrict__ pbuf,
                                                  int njc, size_t pstride,
                                                  const float* __restrict__ lsum,
                                                  int n4, int ftotShift, int fpShift, int act) {
  int idx = blockIdx.x * blockDim.x + threadIdx.x;
  if (idx >= n4) return;
  int idx4 = idx * 4;
  int r = idx4 >> ftotShift;
  int c = idx4 & ((1 << ftotShift) - 1);
  int h = c >> fpShift;
  float li = 1.0f / lsum[h * N_NODES + r];
  float4 v = reinterpret_cast<const float4*>(pbuf)[idx];
  float vv[4] = {v.x, v.y, v.z, v.w};
  for (int q = 1; q < njc; ++q) {
    float4 u = *reinterpret_cast<const float4*>(pbuf + q * pstride + (size_t)idx4);
    vv[0] += u.x; vv[1] += u.y; vv[2] += u.z; vv[3] += u.w;
  }
#pragma unroll
  for (int e = 0; e < 4; ++e) {
    float x = vv[e] * li;
    x = x > 0.0f ? x : exp2f(x * LOG2E) - 1.0f;
    if (act == 1) x = 1.0f / (1.0f + exp2f(-x * LOG2E));
    vv[e] = x;
  }
  reinterpret_cast<float4*>(dst)[idx] = make_float4(vv[0], vv[1], vv[2], vv[3]);
}

// ---------------------------------------------------------------- host
extern "C" void kernel_launch(void* const* d_in, const int* in_sizes, int n_in,
                              void* d_out, int out_size, void* d_ws, size_t ws_size,
                              hipStream_t stream) {
  const float* x     = (const float*)d_in[0];
  const int*   adj   = (const int*)d_in[1];
  const float* W1    = (const float*)d_in[2];
  const float* a1    = (const float*)d_in[3];
  const float* Wo    = (const float*)d_in[4];
  const float* ao    = (const float*)d_in[5];
  const float* W2    = (const float*)d_in[6];
  const float* a2    = (const float*)d_in[7];
  const float* Wo2   = (const float*)d_in[8];
  const float* ao2   = (const float*)d_in[9];
  const float* lin_w = (const float*)d_in[10];
  const float* lin_b = (const float*)d_in[11];
  float* out = (float*)d_out;

  float* ws = (float*)d_ws;
  unsigned int* bits = (unsigned int*)ws;            // 1,179,648 u32
  float* bufA = ws + 1179648;                        // 6144*256
  float* bufB = bufA + 1572864;
  float* Bcat = bufB + 1572864;                      // 65536
  float* f1   = Bcat + 65536;                        // 24576
  float* f2   = f1 + 24576;                          // 24576
  float* lsum = f2 + 24576;                          // 24576
  float* gmaxb = lsum + 24576;                       // 16
  short* WhT  = (short*)(gmaxb + 16);                // 6144*256 fp16 bits
  short* BtW  = WhT + 1572864;                       // 384*256 bf16
  float* pbuf = (float*)(BtW + 98304);               // partial buffers

  const size_t PS256 = (size_t)6144 * 256;
  const size_t PS128 = (size_t)6144 * 128;

  dim3 b256(256);
  dim3 b512(512);

  bitpack_kernel<<<N_NODES, b256, 0, stream>>>(adj, bits);

  // ================= layer 1 multi-head (H=4, Fp=64), elu concat
  repack_W_kernel<<<(4 * 256 * 64 + 255) / 256, b256, 0, stream>>>(W1, Bcat, 4, 256, 64);
  transpose_w_kernel<<<dim3(8, 8), b256, 0, stream>>>(Bcat, BtW, 256, 256);
  hipMemsetAsync(f1, 0, (size_t)2 * 24576 * 4, stream);
  gemm_attn_kernel<1><<<dim3(4, 96), b256, 0, stream>>>(x, BtW, a1, WhT, f1, f2, 256, 256, 64);
  gmax_kernel<<<4, b256, 0, stream>>>(f2, gmaxb);
  hipMemsetAsync(lsum, 0, (size_t)24576 * 4, stream);
  pv_stage_kernel<4, 4><<<dim3(1, 96, 4), b512, 0, stream>>>(f1, f2, gmaxb, bits, WhT, pbuf, lsum, 4, 64);
  act_kernel<<<dim3(1536), b256, 0, stream>>>(bufA, pbuf, 4, PS256, lsum, 6144 * 256 / 4, 8, 6, 0);

  // ================= out-attention 1 (H=1, Fp=256), sigmoid(elu)
  transpose_w_kernel<<<dim3(8, 8), b256, 0, stream>>>(Wo, BtW, 256, 256);
  hipMemsetAsync(f1, 0, (size_t)2 * 24576 * 4, stream);
  gemm_attn_kernel<1><<<dim3(4, 96), b256, 0, stream>>>(bufA, BtW, ao, WhT, f1, f2, 256, 256, 256);
  gmax_kernel<<<1, b256, 0, stream>>>(f2, gmaxb);
  hipMemsetAsync(lsum, 0, (size_t)24576 * 4, stream);
  pv_stage_kernel<8, 8><<<dim3(2, 192, 1), b512, 0, stream>>>(f1, f2, gmaxb, bits, WhT, pbuf, lsum, 1, 256);
  act_kernel<<<dim3(1536), b256, 0, stream>>>(bufB, pbuf, 8, PS256, lsum, 6144 * 256 / 4, 8, 8, 1);

  // ================= layer 2 multi-head (H=4, Fp=32), elu concat
  repack_W_kernel<<<(4 * 256 * 32 + 255) / 256, b256, 0, stream>>>(W2, Bcat, 4, 256, 32);
  transpose_w_kernel<<<dim3(8, 4), b256, 0, stream>>>(Bcat, BtW, 256, 128);
  hipMemsetAsync(f1, 0, (size_t)2 * 24576 * 4, stream);
  gemm_attn_kernel<2><<<dim3(2, 96), b256, 0, stream>>>(bufB, BtW, a2, WhT, f1, f2, 256, 128, 32);
  gmax_kernel<<<4, b256, 0, stream>>>(f2, gmaxb);
  hipMemsetAsync(lsum, 0, (size_t)24576 * 4, stream);
  pv_stage_kernel<2, 4><<<dim3(1, 96, 4), b512, 0, stream>>>(f1, f2, gmaxb, bits, WhT, pbuf, lsum, 4, 32);
  act_kernel<<<dim3(768), b256, 0, stream>>>(bufA, pbuf, 4, PS128, lsum, 6144 * 128 / 4, 7, 5, 0);

  // ================= out-attention 2 (H=1, Fp=128), sigmoid(elu)
  transpose_w_kernel<<<dim3(4, 4), b256, 0, stream>>>(Wo2, BtW, 128, 128);
  hipMemsetAsync(f1, 0, (size_t)2 * 24576 * 4, stream);
  gemm_attn_kernel<1><<<dim3(2, 96), b256, 0, stream>>>(bufA, BtW, ao2, WhT, f1, f2, 128, 128, 128);
  gmax_kernel<<<1, b256, 0, stream>>>(f2, gmaxb);
  hipMemsetAsync(lsum, 0, (size_t)24576 * 4, stream);
  pv_stage_kernel<8, 16><<<dim3(1, 384, 1), b512, 0, stream>>>(f1, f2, gmaxb, bits, WhT, pbuf, lsum, 1, 128);
  act_kernel<<<dim3(768), b256, 0, stream>>>(bufB, pbuf, 16, PS128, lsum, 6144 * 128 / 4, 7, 7, 1);

  // ================= final linear + relu
  transpose_w_kernel<<<dim3(4, 12), b256, 0, stream>>>(lin_w, BtW, 128, 379);
  gemm_mfma_kernel<<<dim3(6, 96), b256, 0, stream>>>(bufB, BtW, out, 128, 379, lin_b, 1);
}

// Round 21
// 347.260 us; speedup vs baseline: 1.0394x; 1.0394x over previous
//
#include <hip/hip_runtime.h>
#include <hip/hip_bf16.h>

#define N_NODES 6144
#define MASK_WORDS 192  // 6144/32
#define LOG2E 1.44269504088896f

using short8 = __attribute__((ext_vector_type(8))) short;
using s16x4  = __attribute__((ext_vector_type(4))) short;
using f32x4  = __attribute__((ext_vector_type(4))) float;
using half2v = __attribute__((ext_vector_type(2))) _Float16;
using half8v = __attribute__((ext_vector_type(8))) _Float16;
struct Half2x4 { half2v v[4]; };

// f32 -> bf16 bits, round-to-nearest-even
__device__ inline unsigned f2bf_u(float f) {
  unsigned u = __builtin_bit_cast(unsigned, f);
  u += 0x7fff + ((u >> 16) & 1);
  return u >> 16;
}
__device__ inline short f2bf(float f) { return (short)f2bf_u(f); }

// async global->LDS, 16B per lane; lds base must be wave-uniform
__device__ inline void glds16(const short* g, short* l) {
  __builtin_amdgcn_global_load_lds(
      (const __attribute__((address_space(1))) unsigned int*)g,
      (__attribute__((address_space(3))) unsigned int*)l, 16, 0, 0);
}

// ---------------------------------------------------------------- bitpack
__global__ __launch_bounds__(256) void bitpack_kernel(const int* __restrict__ adj,
                                                      unsigned int* __restrict__ bits) {
  int row = blockIdx.x;
  int wave = threadIdx.x >> 6, lane = threadIdx.x & 63;
  const int* p = adj + (long)row * N_NODES;
  for (int base = wave * 64; base < N_NODES; base += 256) {
    unsigned long long m = __ballot(p[base + lane] > 0);
    if (lane == 0) {
      bits[row * MASK_WORDS + (base >> 5)] = (unsigned int)m;
      bits[row * MASK_WORDS + (base >> 5) + 1] = (unsigned int)(m >> 32);
    }
  }
}

// ---------------------------------------------------------------- W repack
__global__ __launch_bounds__(256) void repack_W_kernel(const float* __restrict__ W,
                                                       float* __restrict__ B,
                                                       int H, int Fin, int Fp) {
  int idx = blockIdx.x * blockDim.x + threadIdx.x;
  int total = H * Fin * Fp;
  if (idx >= total) return;
  int h = idx / (Fin * Fp);
  int rem = idx - h * (Fin * Fp);
  int k = rem / Fp, c = rem - k * Fp;
  B[k * (H * Fp) + h * Fp + c] = W[idx];
}

// ---------------------------------------------------------------- weight transpose+cvt (bf16)
__global__ __launch_bounds__(256) void transpose_w_kernel(const float* __restrict__ B,
                                                          short* __restrict__ Bt,
                                                          int K, int Nc) {
  __shared__ short t[32][33];
  int k0 = blockIdx.x * 32, c0 = blockIdx.y * 32;
  int tx = threadIdx.x & 31, ty = threadIdx.x >> 5;
  for (int r = ty; r < 32; r += 8) {
    float v = (c0 + tx < Nc) ? B[(size_t)(k0 + r) * Nc + c0 + tx] : 0.0f;
    t[tx][r] = f2bf(v);
  }
  __syncthreads();
  for (int r = ty; r < 32; r += 8)
    Bt[(size_t)(c0 + r) * K + k0 + tx] = t[r][tx];
}

// ---------------------------------------------------------------- MFMA GEMM (final linear only)
__global__ __launch_bounds__(256) void gemm_mfma_kernel(const float* __restrict__ A,
                                                        const short* __restrict__ Bt,
                                                        float* __restrict__ C,
                                                        int K, int Nc,
                                                        const float* __restrict__ bias,
                                                        int act) {
  __shared__ short As[64][40];
  __shared__ short Bs[64][40];
  int m0 = blockIdx.y * 64, n0 = blockIdx.x * 64;
  int tid = threadIdx.x;
  int w = tid >> 6, l = tid & 63, row_l = l & 15, grp = l >> 4;

  f32x4 acc[4] = {f32x4{0,0,0,0}, f32x4{0,0,0,0}, f32x4{0,0,0,0}, f32x4{0,0,0,0}};

  for (int k0 = 0; k0 < K; k0 += 32) {
    __syncthreads();
#pragma unroll
    for (int s = 0; s < 2; ++s) {
      int idx = tid + s * 256;
      int r = idx >> 3, q = idx & 7;
      float4 v = *reinterpret_cast<const float4*>(&A[(size_t)(m0 + r) * K + k0 + q * 4]);
      s16x4 sv = {f2bf(v.x), f2bf(v.y), f2bf(v.z), f2bf(v.w)};
      *reinterpret_cast<s16x4*>(&As[r][q * 4]) = sv;
    }
    {
      int c = tid >> 2, kq = tid & 3;
      *reinterpret_cast<short8*>(&Bs[c][kq * 8]) =
          *reinterpret_cast<const short8*>(&Bt[(size_t)(n0 + c) * K + k0 + kq * 8]);
    }
    __syncthreads();
    short8 a = *reinterpret_cast<const short8*>(&As[w * 16 + row_l][grp * 8]);
#pragma unroll
    for (int n = 0; n < 4; ++n) {
      short8 b = *reinterpret_cast<const short8*>(&Bs[n * 16 + row_l][grp * 8]);
      acc[n] = __builtin_amdgcn_mfma_f32_16x16x32_bf16(a, b, acc[n], 0, 0, 0);
    }
  }

#pragma unroll
  for (int n = 0; n < 4; ++n) {
#pragma unroll
    for (int k = 0; k < 4; ++k) {
      int row = m0 + w * 16 + grp * 4 + k;
      int col = n0 + n * 16 + row_l;
      if (col < Nc) {
        float v = acc[n][k];
        if (bias) v += bias[col];
        if (act == 1) v = fmaxf(v, 0.0f);
        C[(size_t)row * Nc + col] = v;
      }
    }
  }
}

// ---------------------------------------------------------------- attention GEMM (fused epilogue)
template<int HPB>
__global__ __launch_bounds__(256)
void gemm_attn_kernel(const float* __restrict__ A,
                      const short* __restrict__ Bt,
                      const float* __restrict__ avec,
                      short* __restrict__ WhT,
                      float* __restrict__ f1,
                      float* __restrict__ f2,
                      int K, int Nc, int Fp) {
  __shared__ short As[64][40];
  __shared__ short Bs[64][40];
  int m0 = blockIdx.y * 64, n0 = blockIdx.x * 64;
  int tid = threadIdx.x;
  int w = tid >> 6, l = tid & 63, row_l = l & 15, grp = l >> 4;

  f32x4 acc[4] = {f32x4{0,0,0,0}, f32x4{0,0,0,0}, f32x4{0,0,0,0}, f32x4{0,0,0,0}};

  for (int k0 = 0; k0 < K; k0 += 32) {
    __syncthreads();
#pragma unroll
    for (int s = 0; s < 2; ++s) {
      int idx = tid + s * 256;
      int r = idx >> 3, q = idx & 7;
      float4 v = *reinterpret_cast<const float4*>(&A[(size_t)(m0 + r) * K + k0 + q * 4]);
      s16x4 sv = {f2bf(v.x), f2bf(v.y), f2bf(v.z), f2bf(v.w)};
      *reinterpret_cast<s16x4*>(&As[r][q * 4]) = sv;
    }
    {
      int c = tid >> 2, kq = tid & 3;
      *reinterpret_cast<short8*>(&Bs[c][kq * 8]) =
          *reinterpret_cast<const short8*>(&Bt[(size_t)(n0 + c) * K + k0 + kq * 8]);
    }
    __syncthreads();
    short8 a = *reinterpret_cast<const short8*>(&As[w * 16 + row_l][grp * 8]);
#pragma unroll
    for (int n = 0; n < 4; ++n) {
      short8 b = *reinterpret_cast<const short8*>(&Bs[n * 16 + row_l][grp * 8]);
      acc[n] = __builtin_amdgcn_mfma_f32_16x16x32_bf16(a, b, acc[n], 0, 0, 0);
    }
  }

  int baserow = m0 + w * 16 + grp * 4;

#pragma unroll
  for (int n = 0; n < 4; ++n) {
    int col = n0 + n * 16 + row_l;
    _Float16 hv[4];
#pragma unroll
    for (int k = 0; k < 4; ++k) hv[k] = (_Float16)acc[n][k];
    *reinterpret_cast<s16x4*>(&WhT[(size_t)col * N_NODES + baserow]) =
        *reinterpret_cast<s16x4*>(hv);
  }

  constexpr int NPH = 4 / HPB;
#pragma unroll
  for (int half = 0; half < HPB; ++half) {
    int col0 = n0 + half * NPH * 16;
    int h = col0 / Fp;
    float t1[4] = {0, 0, 0, 0}, t2[4] = {0, 0, 0, 0};
#pragma unroll
    for (int nn = 0; nn < NPH; ++nn) {
      int n = half * NPH + nn;
      int col = n0 + n * 16 + row_l;
      int ci = col - h * Fp;
      float av1 = avec[h * 2 * Fp + ci] * LOG2E;
      float av2 = avec[h * 2 * Fp + Fp + ci] * LOG2E;
#pragma unroll
      for (int k = 0; k < 4; ++k) {
        t1[k] += acc[n][k] * av1;
        t2[k] += acc[n][k] * av2;
      }
    }
#pragma unroll
    for (int off = 1; off < 16; off <<= 1) {
#pragma unroll
      for (int k = 0; k < 4; ++k) {
        t1[k] += __shfl_xor(t1[k], off);
        t2[k] += __shfl_xor(t2[k], off);
      }
    }
    if (row_l == 0) {
#pragma unroll
      for (int k = 0; k < 4; ++k) {
        atomicAdd(&f1[h * N_NODES + baserow + k], t1[k]);
        atomicAdd(&f2[h * N_NODES + baserow + k], t2[k]);
      }
    }
  }
}

// ---------------------------------------------------------------- per-head global max of f2
__global__ __launch_bounds__(256) void gmax_kernel(const float* __restrict__ f2s,
                                                   float* __restrict__ gmax) {
  __shared__ float red[4];
  int h = blockIdx.x;
  int tid = threadIdx.x, lane = tid & 63, w = tid >> 6;
  const float* p = f2s + h * N_NODES;
  float m = -3.0e38f;
  for (int j = tid; j < N_NODES; j += 256) m = fmaxf(m, p[j]);
  for (int off = 32; off > 0; off >>= 1) m = fmaxf(m, __shfl_xor(m, off));
  if (lane == 0) red[w] = m;
  __syncthreads();
  if (tid == 0) gmax[h] = fmaxf(fmaxf(red[0], red[1]), fmaxf(red[2], red[3]));
}

// ---------------------------------------------------------------- attention PV (fp16, templated MI)
// 512 threads = 8 waves; each wave owns MI 16-row strips (MI*128 rows/block).
// MI=1 is the proven R19 config; MI=2 shares each V ds_read across 2 MFMAs and
// halves per-work staging/barriers, used ONLY where the grid stays at 768 blocks.
// P = max(Ai'E'_j, Bi'F'_j) & Mlut[wb] (fp16); 64-j stages, triple-buffered glds.
template<int NF, int JC, int MI>
__global__ __launch_bounds__(512)
void pv_stage_kernel(const float* __restrict__ f1s,
                     const float* __restrict__ f2s,
                     const float* __restrict__ gmax,
                     const unsigned int* __restrict__ bits,
                     const short* __restrict__ WhT,
                     float* __restrict__ pbuf,
                     float* __restrict__ lsum,
                     int H, int Fp) {
  constexpr int CH = N_NODES / JC;
  constexpr int COLS = NF * 16;
  constexpr int NS = CH / 64;
  constexpr int CHUNKS = COLS * 8;           // 16B chunks per stage buffer
  constexpr int NITER = (CHUNKS + 511) / 512;
  constexpr int STEP = COLS * 64;            // shorts per buffer
  constexpr int NCH = CH / 384;
  constexpr int RBC = 48 / MI;               // row-blocks per head
  static_assert(NCH * 384 == CH, "chunking");

  __shared__ _Float16 Esh[CH];
  __shared__ _Float16 Fsh[CH];
  __shared__ short Vt[3 * STEP];
  __shared__ uint4 Mlut[256];

  int h = blockIdx.z;
  int cb0 = blockIdx.x * COLS;
  int rb = blockIdx.y % RBC;
  int jc = blockIdx.y / RBC;
  int i0 = rb * (128 * MI);
  int hN = h * N_NODES, hFp = h * Fp;
  int Ftot = H * Fp;
  int tid = threadIdx.x;
  int w = tid >> 6, l = tid & 63;
  int row_l = l & 15, grp = l >> 4;

  int vcol = hFp + cb0;
  const short* Wbase = WhT + (size_t)vcol * N_NODES;
  float gm = gmax[h];

  // ---- prologue: E/F from f2, mask LUT
  {
    const float4* srcF2 = reinterpret_cast<const float4*>(f2s + hN + jc * CH);
    for (int idx = tid; idx < CH / 4; idx += 512) {
      float4 v = srcF2[idx];
      float vv[4] = {v.x, v.y, v.z, v.w};
      _Float16 e4[4], f4[4];
#pragma unroll
      for (int q = 0; q < 4; ++q) {
        float d = vv[q] - gm;
        e4[q] = (_Float16)exp2f(d);
        f4[q] = (_Float16)exp2f(0.2f * d);
      }
      *reinterpret_cast<s16x4*>(&Esh[idx * 4]) = *reinterpret_cast<s16x4*>(e4);
      *reinterpret_cast<s16x4*>(&Fsh[idx * 4]) = *reinterpret_cast<s16x4*>(f4);
    }
    if (tid < 256) {
      unsigned v = tid;
      unsigned w0 = ((v & 1u) ? 0xFFFFu : 0u) | ((v & 2u) ? 0xFFFF0000u : 0u);
      unsigned w1 = ((v & 4u) ? 0xFFFFu : 0u) | ((v & 8u) ? 0xFFFF0000u : 0u);
      unsigned w2 = ((v & 16u) ? 0xFFFFu : 0u) | ((v & 32u) ? 0xFFFF0000u : 0u);
      unsigned w3 = ((v & 64u) ? 0xFFFFu : 0u) | ((v & 128u) ? 0xFFFF0000u : 0u);
      Mlut[v] = make_uint4(w0, w1, w2, w3);
    }
  }
  __syncthreads();

  // pre-swizzled per-lane global offsets per glds iter
  size_t goff[NITER];
#pragma unroll
  for (int it = 0; it < NITER; ++it) {
    int idx = tid + it * 512;
    int c = idx >> 3, sl = idx & 7;
    int slp = sl ^ (c & 7);
    goff[it] = (size_t)(c < COLS ? c : 0) * N_NODES + jc * CH + slp * 8;
  }

  auto issue = [&](int bsel, int j0) {
#pragma unroll
    for (int it = 0; it < NITER; ++it) {
      if (it * 512 + w * 64 < CHUNKS) {
        const short* g = Wbase + goff[it] + j0;
        short* lp = &Vt[bsel * STEP + it * 4096 + w * 512];
        glds16(g, lp);
      }
    }
  };

  issue(0, 0);
  if (NS > 1) issue(1, 64);

  // per-strip row state
  float Ahf[MI], Bhf[MI];
  const unsigned int* mbase[MI];
#pragma unroll
  for (int mi = 0; mi < MI; ++mi) {
    int i = i0 + (mi * 8 + w) * 16 + row_l;
    float fi = f1s[hN + i];
    float m2 = fmaxf(fi + gm, 0.2f * (fi + gm));
    Ahf[mi] = exp2f(fi + gm - m2);
    Bhf[mi] = exp2f(0.2f * (fi + gm) - m2);
    mbase[mi] = bits + (size_t)i * MASK_WORDS + jc * (CH / 32);
  }

  half8v ones8;
#pragma unroll
  for (int q = 0; q < 8; ++q) ones8[q] = (_Float16)1.0f;
  bool needL = (blockIdx.x == 0);

  f32x4 acc[MI][NF];
#pragma unroll
  for (int mi = 0; mi < MI; ++mi)
#pragma unroll
    for (int n = 0; n < NF; ++n) acc[mi][n] = f32x4{0, 0, 0, 0};
  f32x4 accl[MI];
#pragma unroll
  for (int mi = 0; mi < MI; ++mi) accl[mi] = f32x4{0, 0, 0, 0};

  int scount = 0;
#pragma unroll 1
  for (int ch = 0; ch < NCH; ++ch) {
    unsigned mw[MI][12];
#pragma unroll
    for (int mi = 0; mi < MI; ++mi) {
      const uint4* mp = reinterpret_cast<const uint4*>(mbase[mi] + ch * 12);
#pragma unroll
      for (int q = 0; q < 3; ++q) {
        uint4 m = mp[q];
        mw[mi][q * 4 + 0] = m.x; mw[mi][q * 4 + 1] = m.y;
        mw[mi][q * 4 + 2] = m.z; mw[mi][q * 4 + 3] = m.w;
      }
    }
#pragma unroll 1
    for (int s2 = 0; s2 < 6; ++s2) {
      if (scount + 1 == NS) {
        asm volatile("s_waitcnt vmcnt(0)" ::: "memory");
      } else if (NITER == 1) {
        asm volatile("s_waitcnt vmcnt(1)" ::: "memory");
      } else {
        asm volatile("s_waitcnt vmcnt(2)" ::: "memory");
      }
      __builtin_amdgcn_sched_barrier(0);
      __builtin_amdgcn_s_barrier();
      if (scount + 2 < NS) issue((scount + 2) % 3, (scount + 2) * 64);
      const short* vb = &Vt[(scount % 3) * STEP];
#pragma unroll
      for (int hh = 0; hh < 2; ++hh) {
        int jrel = scount * 64 + hh * 32 + grp * 8;
        half8v e8 = *reinterpret_cast<const half8v*>(&Esh[jrel]);
        half8v f8 = *reinterpret_cast<const half8v*>(&Fsh[jrel]);
        Half2x4 E2 = __builtin_bit_cast(Half2x4, e8);
        Half2x4 F2 = __builtin_bit_cast(Half2x4, f8);
        half8v a8[MI];
#pragma unroll
        for (int mi = 0; mi < MI; ++mi) {
          unsigned wb = (mw[mi][s2 * 2 + hh] >> (grp * 8)) & 0xffu;
          uint4 mq4 = Mlut[wb];
          unsigned mka[4] = {mq4.x, mq4.y, mq4.z, mq4.w};
          half2v Ai2 = {(_Float16)Ahf[mi], (_Float16)Ahf[mi]};
          half2v Bi2 = {(_Float16)Bhf[mi], (_Float16)Bhf[mi]};
          Half2x4 P2;
#pragma unroll
          for (int ep = 0; ep < 4; ++ep) {
            half2v p2 = __builtin_elementwise_max(Ai2 * E2.v[ep], Bi2 * F2.v[ep]);
            unsigned pm = __builtin_bit_cast(unsigned, p2) & mka[ep];
            P2.v[ep] = __builtin_bit_cast(half2v, pm);
          }
          a8[mi] = __builtin_bit_cast(half8v, P2);
        }
        int j8s = ((hh << 2) | grp) ^ (row_l & 7);
#pragma unroll
        for (int n = 0; n < NF; ++n) {
          short8 braw = *reinterpret_cast<const short8*>(&vb[(n * 16 + row_l) * 64 + j8s * 8]);
          half8v b8 = __builtin_bit_cast(half8v, braw);
#pragma unroll
          for (int mi = 0; mi < MI; ++mi)
            acc[mi][n] = __builtin_amdgcn_mfma_f32_16x16x32_f16(a8[mi], b8, acc[mi][n], 0, 0, 0);
        }
        if (needL) {
#pragma unroll
          for (int mi = 0; mi < MI; ++mi)
            accl[mi] = __builtin_amdgcn_mfma_f32_16x16x32_f16(a8[mi], ones8, accl[mi], 0, 0, 0);
        }
      }
      ++scount;
    }
  }

  float* outp = pbuf + (size_t)jc * N_NODES * Ftot;
#pragma unroll
  for (int mi = 0; mi < MI; ++mi) {
#pragma unroll
    for (int n = 0; n < NF; ++n) {
#pragma unroll
      for (int k = 0; k < 4; ++k) {
        int r = i0 + (mi * 8 + w) * 16 + grp * 4 + k;
        outp[(size_t)r * Ftot + vcol + n * 16 + row_l] = acc[mi][n][k];
      }
    }
    if (needL && row_l == 0) {
#pragma unroll
      for (int k = 0; k < 4; ++k)
        atomicAdd(&lsum[hN + i0 + (mi * 8 + w) * 16 + grp * 4 + k], accl[mi][k]);
    }
  }
}

// ---------------------------------------------------------------- reduce + activation
__global__ __launch_bounds__(256) void act_kernel(float* __restrict__ dst,
                                                  const float* __restrict__ pbuf,
                                                  int njc, size_t pstride,
                                                  const float* __restrict__ lsum,
                                                  int n4, int ftotShift, int fpShift, int act) {
  int idx = blockIdx.x * blockDim.x + threadIdx.x;
  if (idx >= n4) return;
  int idx4 = idx * 4;
  int r = idx4 >> ftotShift;
  int c = idx4 & ((1 << ftotShift) - 1);
  int h = c >> fpShift;
  float li = 1.0f / lsum[h * N_NODES + r];
  float4 v = reinterpret_cast<const float4*>(pbuf)[idx];
  float vv[4] = {v.x, v.y, v.z, v.w};
  for (int q = 1; q < njc; ++q) {
    float4 u = *reinterpret_cast<const float4*>(pbuf + q * pstride + (size_t)idx4);
    vv[0] += u.x; vv[1] += u.y; vv[2] += u.z; vv[3] += u.w;
  }
#pragma unroll
  for (int e = 0; e < 4; ++e) {
    float x = vv[e] * li;
    x = x > 0.0f ? x : exp2f(x * LOG2E) - 1.0f;
    if (act == 1) x = 1.0f / (1.0f + exp2f(-x * LOG2E));
    vv[e] = x;
  }
  reinterpret_cast<float4*>(dst)[idx] = make_float4(vv[0], vv[1], vv[2], vv[3]);
}

// ---------------------------------------------------------------- host
extern "C" void kernel_launch(void* const* d_in, const int* in_sizes, int n_in,
                              void* d_out, int out_size, void* d_ws, size_t ws_size,
                              hipStream_t stream) {
  const float* x     = (const float*)d_in[0];
  const int*   adj   = (const int*)d_in[1];
  const float* W1    = (const float*)d_in[2];
  const float* a1    = (const float*)d_in[3];
  const float* Wo    = (const float*)d_in[4];
  const float* ao    = (const float*)d_in[5];
  const float* W2    = (const float*)d_in[6];
  const float* a2    = (const float*)d_in[7];
  const float* Wo2   = (const float*)d_in[8];
  const float* ao2   = (const float*)d_in[9];
  const float* lin_w = (const float*)d_in[10];
  const float* lin_b = (const float*)d_in[11];
  float* out = (float*)d_out;

  float* ws = (float*)d_ws;
  unsigned int* bits = (unsigned int*)ws;            // 1,179,648 u32
  float* bufA = ws + 1179648;                        // 6144*256
  float* bufB = bufA + 1572864;
  float* Bcat = bufB + 1572864;                      // 65536
  float* f1   = Bcat + 65536;                        // 24576
  float* f2   = f1 + 24576;                          // 24576
  float* lsum = f2 + 24576;                          // 24576
  float* gmaxb = lsum + 24576;                       // 16
  short* WhT  = (short*)(gmaxb + 16);                // 6144*256 fp16 bits
  short* BtW  = WhT + 1572864;                       // 384*256 bf16
  float* pbuf = (float*)(BtW + 98304);               // partial buffers

  const size_t PS256 = (size_t)6144 * 256;
  const size_t PS128 = (size_t)6144 * 128;

  dim3 b256(256);
  dim3 b512(512);

  bitpack_kernel<<<N_NODES, b256, 0, stream>>>(adj, bits);

  // ================= layer 1 multi-head (H=4, Fp=64), elu concat — MI=2, JC=8 (768 blocks)
  repack_W_kernel<<<(4 * 256 * 64 + 255) / 256, b256, 0, stream>>>(W1, Bcat, 4, 256, 64);
  transpose_w_kernel<<<dim3(8, 8), b256, 0, stream>>>(Bcat, BtW, 256, 256);
  hipMemsetAsync(f1, 0, (size_t)2 * 24576 * 4, stream);
  gemm_attn_kernel<1><<<dim3(4, 96), b256, 0, stream>>>(x, BtW, a1, WhT, f1, f2, 256, 256, 64);
  gmax_kernel<<<4, b256, 0, stream>>>(f2, gmaxb);
  hipMemsetAsync(lsum, 0, (size_t)24576 * 4, stream);
  pv_stage_kernel<4, 8, 2><<<dim3(1, 192, 4), b512, 0, stream>>>(f1, f2, gmaxb, bits, WhT, pbuf, lsum, 4, 64);
  act_kernel<<<dim3(1536), b256, 0, stream>>>(bufA, pbuf, 8, PS256, lsum, 6144 * 256 / 4, 8, 6, 0);

  // ================= out-attention 1 (H=1, Fp=256), sigmoid(elu) — R19 config (MI=1)
  transpose_w_kernel<<<dim3(8, 8), b256, 0, stream>>>(Wo, BtW, 256, 256);
  hipMemsetAsync(f1, 0, (size_t)2 * 24576 * 4, stream);
  gemm_attn_kernel<1><<<dim3(4, 96), b256, 0, stream>>>(bufA, BtW, ao, WhT, f1, f2, 256, 256, 256);
  gmax_kernel<<<1, b256, 0, stream>>>(f2, gmaxb);
  hipMemsetAsync(lsum, 0, (size_t)24576 * 4, stream);
  pv_stage_kernel<8, 8, 1><<<dim3(2, 384, 1), b512, 0, stream>>>(f1, f2, gmaxb, bits, WhT, pbuf, lsum, 1, 256);
  act_kernel<<<dim3(1536), b256, 0, stream>>>(bufB, pbuf, 8, PS256, lsum, 6144 * 256 / 4, 8, 8, 1);

  // ================= layer 2 multi-head (H=4, Fp=32), elu concat — MI=2, JC=8 (768 blocks)
  repack_W_kernel<<<(4 * 256 * 32 + 255) / 256, b256, 0, stream>>>(W2, Bcat, 4, 256, 32);
  transpose_w_kernel<<<dim3(8, 4), b256, 0, stream>>>(Bcat, BtW, 256, 128);
  hipMemsetAsync(f1, 0, (size_t)2 * 24576 * 4, stream);
  gemm_attn_kernel<2><<<dim3(2, 96), b256, 0, stream>>>(bufB, BtW, a2, WhT, f1, f2, 256, 128, 32);
  gmax_kernel<<<4, b256, 0, stream>>>(f2, gmaxb);
  hipMemsetAsync(lsum, 0, (size_t)24576 * 4, stream);
  pv_stage_kernel<2, 8, 2><<<dim3(1, 192, 4), b512, 0, stream>>>(f1, f2, gmaxb, bits, WhT, pbuf, lsum, 4, 32);
  act_kernel<<<dim3(768), b256, 0, stream>>>(bufA, pbuf, 8, PS128, lsum, 6144 * 128 / 4, 7, 5, 0);

  // ================= out-attention 2 (H=1, Fp=128), sigmoid(elu) — R19 config (MI=1)
  transpose_w_kernel<<<dim3(4, 4), b256, 0, stream>>>(Wo2, BtW, 128, 128);
  hipMemsetAsync(f1, 0, (size_t)2 * 24576 * 4, stream);
  gemm_attn_kernel<1><<<dim3(2, 96), b256, 0, stream>>>(bufA, BtW, ao2, WhT, f1, f2, 128, 128, 128);
  gmax_kernel<<<1, b256, 0, stream>>>(f2, gmaxb);
  hipMemsetAsync(lsum, 0, (size_t)24576 * 4, stream);
  pv_stage_kernel<8, 16, 1><<<dim3(1, 768, 1), b512, 0, stream>>>(f1, f2, gmaxb, bits, WhT, pbuf, lsum, 1, 128);
  act_kernel<<<dim3(768), b256, 0, stream>>>(bufB, pbuf, 16, PS128, lsum, 6144 * 128 / 4, 7, 7, 1);

  // ================= final linear + relu
  transpose_w_kernel<<<dim3(4, 12), b256, 0, stream>>>(lin_w, BtW, 128, 379);
  gemm_mfma_kernel<<<dim3(6, 96), b256, 0, stream>>>(bufB, BtW, out, 128, 379, lin_b, 1);
}

// Round 22
// 291.173 us; speedup vs baseline: 1.2396x; 1.1926x over previous
//
#include <hip/hip_runtime.h>
#include <hip/hip_bf16.h>

#define N_NODES 6144
#define MASK_WORDS 192  // 6144/32
#define LOG2E 1.44269504088896f

using short8 = __attribute__((ext_vector_type(8))) short;
using s16x4  = __attribute__((ext_vector_type(4))) short;
using f32x4  = __attribute__((ext_vector_type(4))) float;
using half2v = __attribute__((ext_vector_type(2))) _Float16;
using half8v = __attribute__((ext_vector_type(8))) _Float16;
struct Half2x4 { half2v v[4]; };

// f32 -> bf16 bits, round-to-nearest-even
__device__ inline unsigned f2bf_u(float f) {
  unsigned u = __builtin_bit_cast(unsigned, f);
  u += 0x7fff + ((u >> 16) & 1);
  return u >> 16;
}
__device__ inline short f2bf(float f) { return (short)f2bf_u(f); }

// async global->LDS, 16B per lane; lds base must be wave-uniform
__device__ inline void glds16(const short* g, short* l) {
  __builtin_amdgcn_global_load_lds(
      (const __attribute__((address_space(1))) unsigned int*)g,
      (__attribute__((address_space(3))) unsigned int*)l, 16, 0, 0);
}

// ---------------------------------------------------------------- bitpack
__global__ __launch_bounds__(256) void bitpack_kernel(const int* __restrict__ adj,
                                                      unsigned int* __restrict__ bits) {
  int row = blockIdx.x;
  int wave = threadIdx.x >> 6, lane = threadIdx.x & 63;
  const int* p = adj + (long)row * N_NODES;
  for (int base = wave * 64; base < N_NODES; base += 256) {
    unsigned long long m = __ballot(p[base + lane] > 0);
    if (lane == 0) {
      bits[row * MASK_WORDS + (base >> 5)] = (unsigned int)m;
      bits[row * MASK_WORDS + (base >> 5) + 1] = (unsigned int)(m >> 32);
    }
  }
}

// ---------------------------------------------------------------- W repack
__global__ __launch_bounds__(256) void repack_W_kernel(const float* __restrict__ W,
                                                       float* __restrict__ B,
                                                       int H, int Fin, int Fp) {
  int idx = blockIdx.x * blockDim.x + threadIdx.x;
  int total = H * Fin * Fp;
  if (idx >= total) return;
  int h = idx / (Fin * Fp);
  int rem = idx - h * (Fin * Fp);
  int k = rem / Fp, c = rem - k * Fp;
  B[k * (H * Fp) + h * Fp + c] = W[idx];
}

// ---------------------------------------------------------------- weight transpose+cvt (bf16)
__global__ __launch_bounds__(256) void transpose_w_kernel(const float* __restrict__ B,
                                                          short* __restrict__ Bt,
                                                          int K, int Nc) {
  __shared__ short t[32][33];
  int k0 = blockIdx.x * 32, c0 = blockIdx.y * 32;
  int tx = threadIdx.x & 31, ty = threadIdx.x >> 5;
  for (int r = ty; r < 32; r += 8) {
    float v = (c0 + tx < Nc) ? B[(size_t)(k0 + r) * Nc + c0 + tx] : 0.0f;
    t[tx][r] = f2bf(v);
  }
  __syncthreads();
  for (int r = ty; r < 32; r += 8)
    Bt[(size_t)(c0 + r) * K + k0 + tx] = t[r][tx];
}

// ---------------------------------------------------------------- MFMA GEMM (final linear only)
__global__ __launch_bounds__(256) void gemm_mfma_kernel(const float* __restrict__ A,
                                                        const short* __restrict__ Bt,
                                                        float* __restrict__ C,
                                                        int K, int Nc,
                                                        const float* __restrict__ bias,
                                                        int act) {
  __shared__ short As[64][40];
  __shared__ short Bs[64][40];
  int m0 = blockIdx.y * 64, n0 = blockIdx.x * 64;
  int tid = threadIdx.x;
  int w = tid >> 6, l = tid & 63, row_l = l & 15, grp = l >> 4;

  f32x4 acc[4] = {f32x4{0,0,0,0}, f32x4{0,0,0,0}, f32x4{0,0,0,0}, f32x4{0,0,0,0}};

  for (int k0 = 0; k0 < K; k0 += 32) {
    __syncthreads();
#pragma unroll
    for (int s = 0; s < 2; ++s) {
      int idx = tid + s * 256;
      int r = idx >> 3, q = idx & 7;
      float4 v = *reinterpret_cast<const float4*>(&A[(size_t)(m0 + r) * K + k0 + q * 4]);
      s16x4 sv = {f2bf(v.x), f2bf(v.y), f2bf(v.z), f2bf(v.w)};
      *reinterpret_cast<s16x4*>(&As[r][q * 4]) = sv;
    }
    {
      int c = tid >> 2, kq = tid & 3;
      *reinterpret_cast<short8*>(&Bs[c][kq * 8]) =
          *reinterpret_cast<const short8*>(&Bt[(size_t)(n0 + c) * K + k0 + kq * 8]);
    }
    __syncthreads();
    short8 a = *reinterpret_cast<const short8*>(&As[w * 16 + row_l][grp * 8]);
#pragma unroll
    for (int n = 0; n < 4; ++n) {
      short8 b = *reinterpret_cast<const short8*>(&Bs[n * 16 + row_l][grp * 8]);
      acc[n] = __builtin_amdgcn_mfma_f32_16x16x32_bf16(a, b, acc[n], 0, 0, 0);
    }
  }

#pragma unroll
  for (int n = 0; n < 4; ++n) {
#pragma unroll
    for (int k = 0; k < 4; ++k) {
      int row = m0 + w * 16 + grp * 4 + k;
      int col = n0 + n * 16 + row_l;
      if (col < Nc) {
        float v = acc[n][k];
        if (bias) v += bias[col];
        if (act == 1) v = fmaxf(v, 0.0f);
        C[(size_t)row * Nc + col] = v;
      }
    }
  }
}

// ---------------------------------------------------------------- attention GEMM (fused epilogue)
template<int HPB>
__global__ __launch_bounds__(256)
void gemm_attn_kernel(const float* __restrict__ A,
                      const short* __restrict__ Bt,
                      const float* __restrict__ avec,
                      short* __restrict__ WhT,
                      float* __restrict__ f1,
                      float* __restrict__ f2,
                      int K, int Nc, int Fp) {
  __shared__ short As[64][40];
  __shared__ short Bs[64][40];
  int m0 = blockIdx.y * 64, n0 = blockIdx.x * 64;
  int tid = threadIdx.x;
  int w = tid >> 6, l = tid & 63, row_l = l & 15, grp = l >> 4;

  f32x4 acc[4] = {f32x4{0,0,0,0}, f32x4{0,0,0,0}, f32x4{0,0,0,0}, f32x4{0,0,0,0}};

  for (int k0 = 0; k0 < K; k0 += 32) {
    __syncthreads();
#pragma unroll
    for (int s = 0; s < 2; ++s) {
      int idx = tid + s * 256;
      int r = idx >> 3, q = idx & 7;
      float4 v = *reinterpret_cast<const float4*>(&A[(size_t)(m0 + r) * K + k0 + q * 4]);
      s16x4 sv = {f2bf(v.x), f2bf(v.y), f2bf(v.z), f2bf(v.w)};
      *reinterpret_cast<s16x4*>(&As[r][q * 4]) = sv;
    }
    {
      int c = tid >> 2, kq = tid & 3;
      *reinterpret_cast<short8*>(&Bs[c][kq * 8]) =
          *reinterpret_cast<const short8*>(&Bt[(size_t)(n0 + c) * K + k0 + kq * 8]);
    }
    __syncthreads();
    short8 a = *reinterpret_cast<const short8*>(&As[w * 16 + row_l][grp * 8]);
#pragma unroll
    for (int n = 0; n < 4; ++n) {
      short8 b = *reinterpret_cast<const short8*>(&Bs[n * 16 + row_l][grp * 8]);
      acc[n] = __builtin_amdgcn_mfma_f32_16x16x32_bf16(a, b, acc[n], 0, 0, 0);
    }
  }

  int baserow = m0 + w * 16 + grp * 4;

#pragma unroll
  for (int n = 0; n < 4; ++n) {
    int col = n0 + n * 16 + row_l;
    _Float16 hv[4];
#pragma unroll
    for (int k = 0; k < 4; ++k) hv[k] = (_Float16)acc[n][k];
    *reinterpret_cast<s16x4*>(&WhT[(size_t)col * N_NODES + baserow]) =
        *reinterpret_cast<s16x4*>(hv);
  }

  constexpr int NPH = 4 / HPB;
#pragma unroll
  for (int half = 0; half < HPB; ++half) {
    int col0 = n0 + half * NPH * 16;
    int h = col0 / Fp;
    float t1[4] = {0, 0, 0, 0}, t2[4] = {0, 0, 0, 0};
#pragma unroll
    for (int nn = 0; nn < NPH; ++nn) {
      int n = half * NPH + nn;
      int col = n0 + n * 16 + row_l;
      int ci = col - h * Fp;
      float av1 = avec[h * 2 * Fp + ci] * LOG2E;
      float av2 = avec[h * 2 * Fp + Fp + ci] * LOG2E;
#pragma unroll
      for (int k = 0; k < 4; ++k) {
        t1[k] += acc[n][k] * av1;
        t2[k] += acc[n][k] * av2;
      }
    }
#pragma unroll
    for (int off = 1; off < 16; off <<= 1) {
#pragma unroll
      for (int k = 0; k < 4; ++k) {
        t1[k] += __shfl_xor(t1[k], off);
        t2[k] += __shfl_xor(t2[k], off);
      }
    }
    if (row_l == 0) {
#pragma unroll
      for (int k = 0; k < 4; ++k) {
        atomicAdd(&f1[h * N_NODES + baserow + k], t1[k]);
        atomicAdd(&f2[h * N_NODES + baserow + k], t2[k]);
      }
    }
  }
}

// ---------------------------------------------------------------- per-head global max of f2
__global__ __launch_bounds__(256) void gmax_kernel(const float* __restrict__ f2s,
                                                   float* __restrict__ gmax) {
  __shared__ float red[4];
  int h = blockIdx.x;
  int tid = threadIdx.x, lane = tid & 63, w = tid >> 6;
  const float* p = f2s + h * N_NODES;
  float m = -3.0e38f;
  for (int j = tid; j < N_NODES; j += 256) m = fmaxf(m, p[j]);
  for (int off = 32; off > 0; off >>= 1) m = fmaxf(m, __shfl_xor(m, off));
  if (lane == 0) red[w] = m;
  __syncthreads();
  if (tid == 0) gmax[h] = fmaxf(fmaxf(red[0], red[1]), fmaxf(red[2], red[3]));
}

// ---------------------------------------------------------------- attention PV (fp16, R19 config)
// 512 threads = 8 row-strip waves (128 rows/block). P = max(Ai'E'_j, Bi'F'_j) & LUT.
// 64-j stages, triple-buffered async glds (wave-uniform base), counted vmcnt.
template<int NF, int JC>
__global__ __launch_bounds__(512)
void pv_stage_kernel(const float* __restrict__ f1s,
                     const float* __restrict__ f2s,
                     const float* __restrict__ gmax,
                     const unsigned int* __restrict__ bits,
                     const short* __restrict__ WhT,
                     float* __restrict__ pbuf,
                     float* __restrict__ lsum,
                     int H, int Fp) {
  constexpr int CH = N_NODES / JC;
  constexpr int COLS = NF * 16;
  constexpr int NS = CH / 64;
  constexpr int CHUNKS = COLS * 8;           // 16B chunks per stage buffer
  constexpr int NITER = (CHUNKS + 511) / 512;
  constexpr int STEP = COLS * 64;            // shorts per buffer
  constexpr int NCH = CH / 384;
  static_assert(NCH * 384 == CH, "chunking");

  __shared__ _Float16 Esh[CH];
  __shared__ _Float16 Fsh[CH];
  __shared__ short Vt[3 * STEP];
  __shared__ uint4 Mlut[256];

  int h = blockIdx.z;
  int cb0 = blockIdx.x * COLS;
  int rb = blockIdx.y % 48;
  int jc = blockIdx.y / 48;
  int i0 = rb * 128;
  int hN = h * N_NODES, hFp = h * Fp;
  int Ftot = H * Fp;
  int tid = threadIdx.x;
  int w = tid >> 6, l = tid & 63;
  int row_l = l & 15, grp = l >> 4;

  int vcol = hFp + cb0;
  const short* Wbase = WhT + (size_t)vcol * N_NODES;
  float gm = gmax[h];

  // ---- prologue: E/F from f2, mask LUT
  {
    const float4* srcF2 = reinterpret_cast<const float4*>(f2s + hN + jc * CH);
    for (int idx = tid; idx < CH / 4; idx += 512) {
      float4 v = srcF2[idx];
      float vv[4] = {v.x, v.y, v.z, v.w};
      _Float16 e4[4], f4[4];
#pragma unroll
      for (int q = 0; q < 4; ++q) {
        float d = vv[q] - gm;
        e4[q] = (_Float16)exp2f(d);
        f4[q] = (_Float16)exp2f(0.2f * d);
      }
      *reinterpret_cast<s16x4*>(&Esh[idx * 4]) = *reinterpret_cast<s16x4*>(e4);
      *reinterpret_cast<s16x4*>(&Fsh[idx * 4]) = *reinterpret_cast<s16x4*>(f4);
    }
    if (tid < 256) {
      unsigned v = tid;
      unsigned w0 = ((v & 1u) ? 0xFFFFu : 0u) | ((v & 2u) ? 0xFFFF0000u : 0u);
      unsigned w1 = ((v & 4u) ? 0xFFFFu : 0u) | ((v & 8u) ? 0xFFFF0000u : 0u);
      unsigned w2 = ((v & 16u) ? 0xFFFFu : 0u) | ((v & 32u) ? 0xFFFF0000u : 0u);
      unsigned w3 = ((v & 64u) ? 0xFFFFu : 0u) | ((v & 128u) ? 0xFFFF0000u : 0u);
      Mlut[v] = make_uint4(w0, w1, w2, w3);
    }
  }
  __syncthreads();

  // pre-swizzled per-lane global offsets per glds iter
  size_t goff[NITER];
#pragma unroll
  for (int it = 0; it < NITER; ++it) {
    int idx = tid + it * 512;
    int c = idx >> 3, sl = idx & 7;
    int slp = sl ^ (c & 7);
    goff[it] = (size_t)(c < COLS ? c : 0) * N_NODES + jc * CH + slp * 8;
  }

  auto issue = [&](int bsel, int j0) {
#pragma unroll
    for (int it = 0; it < NITER; ++it) {
      if (it * 512 + w * 64 < CHUNKS) {
        const short* g = Wbase + goff[it] + j0;
        short* lp = &Vt[bsel * STEP + it * 4096 + w * 512];
        glds16(g, lp);
      }
    }
  };

  issue(0, 0);
  if (NS > 1) issue(1, 64);

  int i = i0 + w * 16 + row_l;
  float fi = f1s[hN + i];
  float mi = fmaxf(fi + gm, 0.2f * (fi + gm));
  _Float16 Aih = (_Float16)exp2f(fi + gm - mi);
  _Float16 Bih = (_Float16)exp2f(0.2f * (fi + gm) - mi);
  half2v Ai2 = {Aih, Aih};
  half2v Bi2 = {Bih, Bih};
  const unsigned int* mbase = bits + (size_t)i * MASK_WORDS + jc * (CH / 32);

  half8v ones8;
#pragma unroll
  for (int q = 0; q < 8; ++q) ones8[q] = (_Float16)1.0f;
  bool needL = (blockIdx.x == 0);

  f32x4 acc[NF];
#pragma unroll
  for (int n = 0; n < NF; ++n) acc[n] = f32x4{0, 0, 0, 0};
  f32x4 accl = f32x4{0, 0, 0, 0};

  int scount = 0;
#pragma unroll 1
  for (int ch = 0; ch < NCH; ++ch) {
    unsigned mw[12];
    {
      const uint4* mp = reinterpret_cast<const uint4*>(mbase + ch * 12);
#pragma unroll
      for (int q = 0; q < 3; ++q) {
        uint4 m = mp[q];
        mw[q * 4 + 0] = m.x; mw[q * 4 + 1] = m.y;
        mw[q * 4 + 2] = m.z; mw[q * 4 + 3] = m.w;
      }
    }
#pragma unroll 1
    for (int s2 = 0; s2 < 6; ++s2) {
      if (scount + 1 == NS) {
        asm volatile("s_waitcnt vmcnt(0)" ::: "memory");
      } else if (NITER == 1) {
        asm volatile("s_waitcnt vmcnt(1)" ::: "memory");
      } else {
        asm volatile("s_waitcnt vmcnt(2)" ::: "memory");
      }
      __builtin_amdgcn_sched_barrier(0);
      __builtin_amdgcn_s_barrier();
      if (scount + 2 < NS) issue((scount + 2) % 3, (scount + 2) * 64);
      const short* vb = &Vt[(scount % 3) * STEP];
#pragma unroll
      for (int hh = 0; hh < 2; ++hh) {
        unsigned wb = (mw[s2 * 2 + hh] >> (grp * 8)) & 0xffu;
        uint4 mq4 = Mlut[wb];
        unsigned mka[4] = {mq4.x, mq4.y, mq4.z, mq4.w};
        int jrel = scount * 64 + hh * 32 + grp * 8;
        half8v e8 = *reinterpret_cast<const half8v*>(&Esh[jrel]);
        half8v f8 = *reinterpret_cast<const half8v*>(&Fsh[jrel]);
        Half2x4 E2 = __builtin_bit_cast(Half2x4, e8);
        Half2x4 F2 = __builtin_bit_cast(Half2x4, f8);
        Half2x4 P2;
#pragma unroll
        for (int ep = 0; ep < 4; ++ep) {
          half2v p2 = __builtin_elementwise_max(Ai2 * E2.v[ep], Bi2 * F2.v[ep]);
          unsigned pm = __builtin_bit_cast(unsigned, p2) & mka[ep];
          P2.v[ep] = __builtin_bit_cast(half2v, pm);
        }
        half8v a8 = __builtin_bit_cast(half8v, P2);
        int j8s = ((hh << 2) | grp) ^ (row_l & 7);
#pragma unroll
        for (int n = 0; n < NF; ++n) {
          short8 braw = *reinterpret_cast<const short8*>(&vb[(n * 16 + row_l) * 64 + j8s * 8]);
          half8v b8 = __builtin_bit_cast(half8v, braw);
          acc[n] = __builtin_amdgcn_mfma_f32_16x16x32_f16(a8, b8, acc[n], 0, 0, 0);
        }
        if (needL)
          accl = __builtin_amdgcn_mfma_f32_16x16x32_f16(a8, ones8, accl, 0, 0, 0);
      }
      ++scount;
    }
  }

  float* outp = pbuf + (size_t)jc * N_NODES * Ftot;
#pragma unroll
  for (int n = 0; n < NF; ++n) {
#pragma unroll
    for (int k = 0; k < 4; ++k) {
      int r = i0 + w * 16 + grp * 4 + k;
      outp[(size_t)r * Ftot + vcol + n * 16 + row_l] = acc[n][k];
    }
  }
  if (needL && row_l == 0) {
#pragma unroll
    for (int k = 0; k < 4; ++k)
      atomicAdd(&lsum[hN + i0 + w * 16 + grp * 4 + k], accl[k]);
  }
}

// ---------------------------------------------------------------- reduce + activation
__global__ __launch_bounds__(256) void act_kernel(float* __restrict__ dst,
                                                  const float* __restrict__ pbuf,
                                                  int njc, size_t pstride,
                                                  const float* __restrict__ lsum,
                                                  int n4, int ftotShift, int fpShift, int act) {
  int idx = blockIdx.x * blockDim.x + threadIdx.x;
  if (idx >= n4) return;
  int idx4 = idx * 4;
  int r = idx4 >> ftotShift;
  int c = idx4 & ((1 << ftotShift) - 1);
  int h = c >> fpShift;
  float li = 1.0f / lsum[h * N_NODES + r];
  float4 v = reinterpret_cast<const float4*>(pbuf)[idx];
  float vv[4] = {v.x, v.y, v.z, v.w};
  for (int q = 1; q < njc; ++q) {
    float4 u = *reinterpret_cast<const float4*>(pbuf + q * pstride + (size_t)idx4);
    vv[0] += u.x; vv[1] += u.y; vv[2] += u.z; vv[3] += u.w;
  }
#pragma unroll
  for (int e = 0; e < 4; ++e) {
    float x = vv[e] * li;
    x = x > 0.0f ? x : exp2f(x * LOG2E) - 1.0f;
    if (act == 1) x = 1.0f / (1.0f + exp2f(-x * LOG2E));
    vv[e] = x;
  }
  reinterpret_cast<float4*>(dst)[idx] = make_float4(vv[0], vv[1], vv[2], vv[3]);
}

// ---------------------------------------------------------------- host
extern "C" void kernel_launch(void* const* d_in, const int* in_sizes, int n_in,
                              void* d_out, int out_size, void* d_ws, size_t ws_size,
                              hipStream_t stream) {
  const float* x     = (const float*)d_in[0];
  const int*   adj   = (const int*)d_in[1];
  const float* W1    = (const float*)d_in[2];
  const float* a1    = (const float*)d_in[3];
  const float* Wo    = (const float*)d_in[4];
  const float* ao    = (const float*)d_in[5];
  const float* W2    = (const float*)d_in[6];
  const float* a2    = (const float*)d_in[7];
  const float* Wo2   = (const float*)d_in[8];
  const float* ao2   = (const float*)d_in[9];
  const float* lin_w = (const float*)d_in[10];
  const float* lin_b = (const float*)d_in[11];
  float* out = (float*)d_out;

  float* ws = (float*)d_ws;
  unsigned int* bits = (unsigned int*)ws;            // 1,179,648 u32
  float* bufA = ws + 1179648;                        // 6144*256
  float* bufB = bufA + 1572864;
  float* Bcat = bufB + 1572864;                      // 65536
  float* f1   = Bcat + 65536;                        // 24576
  float* f2   = f1 + 24576;                          // 24576
  float* lsum = f2 + 24576;                          // 24576 (contiguous: one memset zeroes f1,f2,lsum)
  float* gmaxb = lsum + 24576;                       // 16
  short* WhT  = (short*)(gmaxb + 16);                // 6144*256 fp16 bits
  short* BtW  = WhT + 1572864;                       // 384*256 bf16
  float* pbuf = (float*)(BtW + 98304);               // partial buffers

  const size_t PS256 = (size_t)6144 * 256;
  const size_t PS128 = (size_t)6144 * 128;

  dim3 b256(256);
  dim3 b512(512);

  bitpack_kernel<<<N_NODES, b256, 0, stream>>>(adj, bits);

  // ================= layer 1 multi-head (H=4, Fp=64), elu concat
  repack_W_kernel<<<(4 * 256 * 64 + 255) / 256, b256, 0, stream>>>(W1, Bcat, 4, 256, 64);
  transpose_w_kernel<<<dim3(8, 8), b256, 0, stream>>>(Bcat, BtW, 256, 256);
  hipMemsetAsync(f1, 0, (size_t)3 * 24576 * 4, stream);   // f1,f2,lsum
  gemm_attn_kernel<1><<<dim3(4, 96), b256, 0, stream>>>(x, BtW, a1, WhT, f1, f2, 256, 256, 64);
  gmax_kernel<<<4, b256, 0, stream>>>(f2, gmaxb);
  pv_stage_kernel<4, 4><<<dim3(1, 192, 4), b512, 0, stream>>>(f1, f2, gmaxb, bits, WhT, pbuf, lsum, 4, 64);
  act_kernel<<<dim3(1536), b256, 0, stream>>>(bufA, pbuf, 4, PS256, lsum, 6144 * 256 / 4, 8, 6, 0);

  // ================= out-attention 1 (H=1, Fp=256), sigmoid(elu)
  transpose_w_kernel<<<dim3(8, 8), b256, 0, stream>>>(Wo, BtW, 256, 256);
  hipMemsetAsync(f1, 0, (size_t)3 * 24576 * 4, stream);
  gemm_attn_kernel<1><<<dim3(4, 96), b256, 0, stream>>>(bufA, BtW, ao, WhT, f1, f2, 256, 256, 256);
  gmax_kernel<<<1, b256, 0, stream>>>(f2, gmaxb);
  pv_stage_kernel<8, 8><<<dim3(2, 384, 1), b512, 0, stream>>>(f1, f2, gmaxb, bits, WhT, pbuf, lsum, 1, 256);
  act_kernel<<<dim3(1536), b256, 0, stream>>>(bufB, pbuf, 8, PS256, lsum, 6144 * 256 / 4, 8, 8, 1);

  // ================= layer 2 multi-head (H=4, Fp=32), elu concat
  repack_W_kernel<<<(4 * 256 * 32 + 255) / 256, b256, 0, stream>>>(W2, Bcat, 4, 256, 32);
  transpose_w_kernel<<<dim3(8, 4), b256, 0, stream>>>(Bcat, BtW, 256, 128);
  hipMemsetAsync(f1, 0, (size_t)3 * 24576 * 4, stream);
  gemm_attn_kernel<2><<<dim3(2, 96), b256, 0, stream>>>(bufB, BtW, a2, WhT, f1, f2, 256, 128, 32);
  gmax_kernel<<<4, b256, 0, stream>>>(f2, gmaxb);
  pv_stage_kernel<2, 4><<<dim3(1, 192, 4), b512, 0, stream>>>(f1, f2, gmaxb, bits, WhT, pbuf, lsum, 4, 32);
  act_kernel<<<dim3(768), b256, 0, stream>>>(bufA, pbuf, 4, PS128, lsum, 6144 * 128 / 4, 7, 5, 0);

  // ================= out-attention 2 (H=1, Fp=128), sigmoid(elu)
  transpose_w_kernel<<<dim3(4, 4), b256, 0, stream>>>(Wo2, BtW, 128, 128);
  hipMemsetAsync(f1, 0, (size_t)3 * 24576 * 4, stream);
  gemm_attn_kernel<1><<<dim3(2, 96), b256, 0, stream>>>(bufA, BtW, ao2, WhT, f1, f2, 128, 128, 128);
  gmax_kernel<<<1, b256, 0, stream>>>(f2, gmaxb);
  pv_stage_kernel<8, 16><<<dim3(1, 768, 1), b512, 0, stream>>>(f1, f2, gmaxb, bits, WhT, pbuf, lsum, 1, 128);
  act_kernel<<<dim3(768), b256, 0, stream>>>(bufB, pbuf, 16, PS128, lsum, 6144 * 128 / 4, 7, 7, 1);

  // ================= final linear + relu
  transpose_w_kernel<<<dim3(4, 12), b256, 0, stream>>>(lin_w, BtW, 128, 379);
  gemm_mfma_kernel<<<dim3(6, 96), b256, 0, stream>>>(bufB, BtW, out, 128, 379, lin_b, 1);
}

// Round 23
// 281.950 us; speedup vs baseline: 1.2801x; 1.0327x over previous
//
#include <hip/hip_runtime.h>
#include <hip/hip_bf16.h>

#define N_NODES 6144
#define MASK_WORDS 192  // 6144/32
#define LOG2E 1.44269504088896f

using short8 = __attribute__((ext_vector_type(8))) short;
using s16x4  = __attribute__((ext_vector_type(4))) short;
using f32x4  = __attribute__((ext_vector_type(4))) float;
using half2v = __attribute__((ext_vector_type(2))) _Float16;
using half8v = __attribute__((ext_vector_type(8))) _Float16;
using half4v = __attribute__((ext_vector_type(4))) _Float16;
struct Half2x4 { half2v v[4]; };

// f32 -> bf16 bits, round-to-nearest-even
__device__ inline unsigned f2bf_u(float f) {
  unsigned u = __builtin_bit_cast(unsigned, f);
  u += 0x7fff + ((u >> 16) & 1);
  return u >> 16;
}
__device__ inline short f2bf(float f) { return (short)f2bf_u(f); }

// async global->LDS, 16B per lane; lds base must be wave-uniform
__device__ inline void glds16(const short* g, short* l) {
  __builtin_amdgcn_global_load_lds(
      (const __attribute__((address_space(1))) unsigned int*)g,
      (__attribute__((address_space(3))) unsigned int*)l, 16, 0, 0);
}

// ---------------------------------------------------------------- bitpack
__global__ __launch_bounds__(256) void bitpack_kernel(const int* __restrict__ adj,
                                                      unsigned int* __restrict__ bits) {
  int row = blockIdx.x;
  int wave = threadIdx.x >> 6, lane = threadIdx.x & 63;
  const int* p = adj + (long)row * N_NODES;
  for (int base = wave * 64; base < N_NODES; base += 256) {
    unsigned long long m = __ballot(p[base + lane] > 0);
    if (lane == 0) {
      bits[row * MASK_WORDS + (base >> 5)] = (unsigned int)m;
      bits[row * MASK_WORDS + (base >> 5) + 1] = (unsigned int)(m >> 32);
    }
  }
}

// ---------------------------------------------------------------- W repack
__global__ __launch_bounds__(256) void repack_W_kernel(const float* __restrict__ W,
                                                       float* __restrict__ B,
                                                       int H, int Fin, int Fp) {
  int idx = blockIdx.x * blockDim.x + threadIdx.x;
  int total = H * Fin * Fp;
  if (idx >= total) return;
  int h = idx / (Fin * Fp);
  int rem = idx - h * (Fin * Fp);
  int k = rem / Fp, c = rem - k * Fp;
  B[k * (H * Fp) + h * Fp + c] = W[idx];
}

// ---------------------------------------------------------------- weight transpose+cvt (bf16)
__global__ __launch_bounds__(256) void transpose_w_kernel(const float* __restrict__ B,
                                                          short* __restrict__ Bt,
                                                          int K, int Nc) {
  __shared__ short t[32][33];
  int k0 = blockIdx.x * 32, c0 = blockIdx.y * 32;
  int tx = threadIdx.x & 31, ty = threadIdx.x >> 5;
  for (int r = ty; r < 32; r += 8) {
    float v = (c0 + tx < Nc) ? B[(size_t)(k0 + r) * Nc + c0 + tx] : 0.0f;
    t[tx][r] = f2bf(v);
  }
  __syncthreads();
  for (int r = ty; r < 32; r += 8)
    Bt[(size_t)(c0 + r) * K + k0 + tx] = t[r][tx];
}

// ---------------------------------------------------------------- MFMA GEMM (final linear only)
__global__ __launch_bounds__(256) void gemm_mfma_kernel(const float* __restrict__ A,
                                                        const short* __restrict__ Bt,
                                                        float* __restrict__ C,
                                                        int K, int Nc,
                                                        const float* __restrict__ bias,
                                                        int act) {
  __shared__ short As[64][40];
  __shared__ short Bs[64][40];
  int m0 = blockIdx.y * 64, n0 = blockIdx.x * 64;
  int tid = threadIdx.x;
  int w = tid >> 6, l = tid & 63, row_l = l & 15, grp = l >> 4;

  f32x4 acc[4] = {f32x4{0,0,0,0}, f32x4{0,0,0,0}, f32x4{0,0,0,0}, f32x4{0,0,0,0}};

  for (int k0 = 0; k0 < K; k0 += 32) {
    __syncthreads();
#pragma unroll
    for (int s = 0; s < 2; ++s) {
      int idx = tid + s * 256;
      int r = idx >> 3, q = idx & 7;
      float4 v = *reinterpret_cast<const float4*>(&A[(size_t)(m0 + r) * K + k0 + q * 4]);
      s16x4 sv = {f2bf(v.x), f2bf(v.y), f2bf(v.z), f2bf(v.w)};
      *reinterpret_cast<s16x4*>(&As[r][q * 4]) = sv;
    }
    {
      int c = tid >> 2, kq = tid & 3;
      *reinterpret_cast<short8*>(&Bs[c][kq * 8]) =
          *reinterpret_cast<const short8*>(&Bt[(size_t)(n0 + c) * K + k0 + kq * 8]);
    }
    __syncthreads();
    short8 a = *reinterpret_cast<const short8*>(&As[w * 16 + row_l][grp * 8]);
#pragma unroll
    for (int n = 0; n < 4; ++n) {
      short8 b = *reinterpret_cast<const short8*>(&Bs[n * 16 + row_l][grp * 8]);
      acc[n] = __builtin_amdgcn_mfma_f32_16x16x32_bf16(a, b, acc[n], 0, 0, 0);
    }
  }

#pragma unroll
  for (int n = 0; n < 4; ++n) {
#pragma unroll
    for (int k = 0; k < 4; ++k) {
      int row = m0 + w * 16 + grp * 4 + k;
      int col = n0 + n * 16 + row_l;
      if (col < Nc) {
        float v = acc[n][k];
        if (bias) v += bias[col];
        if (act == 1) v = fmaxf(v, 0.0f);
        C[(size_t)row * Nc + col] = v;
      }
    }
  }
}

// ---------------------------------------------------------------- attention GEMM (fused epilogue)
template<int HPB>
__global__ __launch_bounds__(256)
void gemm_attn_kernel(const float* __restrict__ A,
                      const short* __restrict__ Bt,
                      const float* __restrict__ avec,
                      short* __restrict__ WhT,
                      float* __restrict__ f1,
                      float* __restrict__ f2,
                      int K, int Nc, int Fp) {
  __shared__ short As[64][40];
  __shared__ short Bs[64][40];
  int m0 = blockIdx.y * 64, n0 = blockIdx.x * 64;
  int tid = threadIdx.x;
  int w = tid >> 6, l = tid & 63, row_l = l & 15, grp = l >> 4;

  f32x4 acc[4] = {f32x4{0,0,0,0}, f32x4{0,0,0,0}, f32x4{0,0,0,0}, f32x4{0,0,0,0}};

  for (int k0 = 0; k0 < K; k0 += 32) {
    __syncthreads();
#pragma unroll
    for (int s = 0; s < 2; ++s) {
      int idx = tid + s * 256;
      int r = idx >> 3, q = idx & 7;
      float4 v = *reinterpret_cast<const float4*>(&A[(size_t)(m0 + r) * K + k0 + q * 4]);
      s16x4 sv = {f2bf(v.x), f2bf(v.y), f2bf(v.z), f2bf(v.w)};
      *reinterpret_cast<s16x4*>(&As[r][q * 4]) = sv;
    }
    {
      int c = tid >> 2, kq = tid & 3;
      *reinterpret_cast<short8*>(&Bs[c][kq * 8]) =
          *reinterpret_cast<const short8*>(&Bt[(size_t)(n0 + c) * K + k0 + kq * 8]);
    }
    __syncthreads();
    short8 a = *reinterpret_cast<const short8*>(&As[w * 16 + row_l][grp * 8]);
#pragma unroll
    for (int n = 0; n < 4; ++n) {
      short8 b = *reinterpret_cast<const short8*>(&Bs[n * 16 + row_l][grp * 8]);
      acc[n] = __builtin_amdgcn_mfma_f32_16x16x32_bf16(a, b, acc[n], 0, 0, 0);
    }
  }

  int baserow = m0 + w * 16 + grp * 4;

#pragma unroll
  for (int n = 0; n < 4; ++n) {
    int col = n0 + n * 16 + row_l;
    _Float16 hv[4];
#pragma unroll
    for (int k = 0; k < 4; ++k) hv[k] = (_Float16)acc[n][k];
    *reinterpret_cast<s16x4*>(&WhT[(size_t)col * N_NODES + baserow]) =
        *reinterpret_cast<s16x4*>(hv);
  }

  constexpr int NPH = 4 / HPB;
#pragma unroll
  for (int half = 0; half < HPB; ++half) {
    int col0 = n0 + half * NPH * 16;
    int h = col0 / Fp;
    float t1[4] = {0, 0, 0, 0}, t2[4] = {0, 0, 0, 0};
#pragma unroll
    for (int nn = 0; nn < NPH; ++nn) {
      int n = half * NPH + nn;
      int col = n0 + n * 16 + row_l;
      int ci = col - h * Fp;
      float av1 = avec[h * 2 * Fp + ci] * LOG2E;
      float av2 = avec[h * 2 * Fp + Fp + ci] * LOG2E;
#pragma unroll
      for (int k = 0; k < 4; ++k) {
        t1[k] += acc[n][k] * av1;
        t2[k] += acc[n][k] * av2;
      }
    }
#pragma unroll
    for (int off = 1; off < 16; off <<= 1) {
#pragma unroll
      for (int k = 0; k < 4; ++k) {
        t1[k] += __shfl_xor(t1[k], off);
        t2[k] += __shfl_xor(t2[k], off);
      }
    }
    if (row_l == 0) {
#pragma unroll
      for (int k = 0; k < 4; ++k) {
        atomicAdd(&f1[h * N_NODES + baserow + k], t1[k]);
        atomicAdd(&f2[h * N_NODES + baserow + k], t2[k]);
      }
    }
  }
}

// ---------------------------------------------------------------- per-head global max of f2
__global__ __launch_bounds__(256) void gmax_kernel(const float* __restrict__ f2s,
                                                   float* __restrict__ gmax) {
  __shared__ float red[4];
  int h = blockIdx.x;
  int tid = threadIdx.x, lane = tid & 63, w = tid >> 6;
  const float* p = f2s + h * N_NODES;
  float m = -3.0e38f;
  for (int j = tid; j < N_NODES; j += 256) m = fmaxf(m, p[j]);
  for (int off = 32; off > 0; off >>= 1) m = fmaxf(m, __shfl_xor(m, off));
  if (lane == 0) red[w] = m;
  __syncthreads();
  if (tid == 0) gmax[h] = fmaxf(fmaxf(red[0], red[1]), fmaxf(red[2], red[3]));
}

// ---------------------------------------------------------------- attention PV (fp16, fp16 partials)
// 512 threads = 8 row-strip waves (128 rows/block). P = max(Ai'E'_j, Bi'F'_j) & LUT.
// 64-j stages, triple-buffered async glds (wave-uniform base), counted vmcnt.
// Partials stored fp16 (halves pbuf round-trip traffic); act accumulates f32.
template<int NF, int JC>
__global__ __launch_bounds__(512)
void pv_stage_kernel(const float* __restrict__ f1s,
                     const float* __restrict__ f2s,
                     const float* __restrict__ gmax,
                     const unsigned int* __restrict__ bits,
                     const short* __restrict__ WhT,
                     _Float16* __restrict__ pbuf,
                     float* __restrict__ lsum,
                     int H, int Fp) {
  constexpr int CH = N_NODES / JC;
  constexpr int COLS = NF * 16;
  constexpr int NS = CH / 64;
  constexpr int CHUNKS = COLS * 8;           // 16B chunks per stage buffer
  constexpr int NITER = (CHUNKS + 511) / 512;
  constexpr int STEP = COLS * 64;            // shorts per buffer
  constexpr int NCH = CH / 384;
  static_assert(NCH * 384 == CH, "chunking");

  __shared__ _Float16 Esh[CH];
  __shared__ _Float16 Fsh[CH];
  __shared__ short Vt[3 * STEP];
  __shared__ uint4 Mlut[256];

  int h = blockIdx.z;
  int cb0 = blockIdx.x * COLS;
  int rb = blockIdx.y % 48;
  int jc = blockIdx.y / 48;
  int i0 = rb * 128;
  int hN = h * N_NODES, hFp = h * Fp;
  int Ftot = H * Fp;
  int tid = threadIdx.x;
  int w = tid >> 6, l = tid & 63;
  int row_l = l & 15, grp = l >> 4;

  int vcol = hFp + cb0;
  const short* Wbase = WhT + (size_t)vcol * N_NODES;
  float gm = gmax[h];

  // ---- prologue: E/F from f2, mask LUT
  {
    const float4* srcF2 = reinterpret_cast<const float4*>(f2s + hN + jc * CH);
    for (int idx = tid; idx < CH / 4; idx += 512) {
      float4 v = srcF2[idx];
      float vv[4] = {v.x, v.y, v.z, v.w};
      _Float16 e4[4], f4[4];
#pragma unroll
      for (int q = 0; q < 4; ++q) {
        float d = vv[q] - gm;
        e4[q] = (_Float16)exp2f(d);
        f4[q] = (_Float16)exp2f(0.2f * d);
      }
      *reinterpret_cast<s16x4*>(&Esh[idx * 4]) = *reinterpret_cast<s16x4*>(e4);
      *reinterpret_cast<s16x4*>(&Fsh[idx * 4]) = *reinterpret_cast<s16x4*>(f4);
    }
    if (tid < 256) {
      unsigned v = tid;
      unsigned w0 = ((v & 1u) ? 0xFFFFu : 0u) | ((v & 2u) ? 0xFFFF0000u : 0u);
      unsigned w1 = ((v & 4u) ? 0xFFFFu : 0u) | ((v & 8u) ? 0xFFFF0000u : 0u);
      unsigned w2 = ((v & 16u) ? 0xFFFFu : 0u) | ((v & 32u) ? 0xFFFF0000u : 0u);
      unsigned w3 = ((v & 64u) ? 0xFFFFu : 0u) | ((v & 128u) ? 0xFFFF0000u : 0u);
      Mlut[v] = make_uint4(w0, w1, w2, w3);
    }
  }
  __syncthreads();

  // pre-swizzled per-lane global offsets per glds iter
  size_t goff[NITER];
#pragma unroll
  for (int it = 0; it < NITER; ++it) {
    int idx = tid + it * 512;
    int c = idx >> 3, sl = idx & 7;
    int slp = sl ^ (c & 7);
    goff[it] = (size_t)(c < COLS ? c : 0) * N_NODES + jc * CH + slp * 8;
  }

  auto issue = [&](int bsel, int j0) {
#pragma unroll
    for (int it = 0; it < NITER; ++it) {
      if (it * 512 + w * 64 < CHUNKS) {
        const short* g = Wbase + goff[it] + j0;
        short* lp = &Vt[bsel * STEP + it * 4096 + w * 512];
        glds16(g, lp);
      }
    }
  };

  issue(0, 0);
  if (NS > 1) issue(1, 64);

  int i = i0 + w * 16 + row_l;
  float fi = f1s[hN + i];
  float mi = fmaxf(fi + gm, 0.2f * (fi + gm));
  _Float16 Aih = (_Float16)exp2f(fi + gm - mi);
  _Float16 Bih = (_Float16)exp2f(0.2f * (fi + gm) - mi);
  half2v Ai2 = {Aih, Aih};
  half2v Bi2 = {Bih, Bih};
  const unsigned int* mbase = bits + (size_t)i * MASK_WORDS + jc * (CH / 32);

  half8v ones8;
#pragma unroll
  for (int q = 0; q < 8; ++q) ones8[q] = (_Float16)1.0f;
  bool needL = (blockIdx.x == 0);

  f32x4 acc[NF];
#pragma unroll
  for (int n = 0; n < NF; ++n) acc[n] = f32x4{0, 0, 0, 0};
  f32x4 accl = f32x4{0, 0, 0, 0};

  int scount = 0;
#pragma unroll 1
  for (int ch = 0; ch < NCH; ++ch) {
    unsigned mw[12];
    {
      const uint4* mp = reinterpret_cast<const uint4*>(mbase + ch * 12);
#pragma unroll
      for (int q = 0; q < 3; ++q) {
        uint4 m = mp[q];
        mw[q * 4 + 0] = m.x; mw[q * 4 + 1] = m.y;
        mw[q * 4 + 2] = m.z; mw[q * 4 + 3] = m.w;
      }
    }
#pragma unroll 1
    for (int s2 = 0; s2 < 6; ++s2) {
      if (scount + 1 == NS) {
        asm volatile("s_waitcnt vmcnt(0)" ::: "memory");
      } else if (NITER == 1) {
        asm volatile("s_waitcnt vmcnt(1)" ::: "memory");
      } else {
        asm volatile("s_waitcnt vmcnt(2)" ::: "memory");
      }
      __builtin_amdgcn_sched_barrier(0);
      __builtin_amdgcn_s_barrier();
      if (scount + 2 < NS) issue((scount + 2) % 3, (scount + 2) * 64);
      const short* vb = &Vt[(scount % 3) * STEP];
#pragma unroll
      for (int hh = 0; hh < 2; ++hh) {
        unsigned wb = (mw[s2 * 2 + hh] >> (grp * 8)) & 0xffu;
        uint4 mq4 = Mlut[wb];
        unsigned mka[4] = {mq4.x, mq4.y, mq4.z, mq4.w};
        int jrel = scount * 64 + hh * 32 + grp * 8;
        half8v e8 = *reinterpret_cast<const half8v*>(&Esh[jrel]);
        half8v f8 = *reinterpret_cast<const half8v*>(&Fsh[jrel]);
        Half2x4 E2 = __builtin_bit_cast(Half2x4, e8);
        Half2x4 F2 = __builtin_bit_cast(Half2x4, f8);
        Half2x4 P2;
#pragma unroll
        for (int ep = 0; ep < 4; ++ep) {
          half2v p2 = __builtin_elementwise_max(Ai2 * E2.v[ep], Bi2 * F2.v[ep]);
          unsigned pm = __builtin_bit_cast(unsigned, p2) & mka[ep];
          P2.v[ep] = __builtin_bit_cast(half2v, pm);
        }
        half8v a8 = __builtin_bit_cast(half8v, P2);
        int j8s = ((hh << 2) | grp) ^ (row_l & 7);
#pragma unroll
        for (int n = 0; n < NF; ++n) {
          short8 braw = *reinterpret_cast<const short8*>(&vb[(n * 16 + row_l) * 64 + j8s * 8]);
          half8v b8 = __builtin_bit_cast(half8v, braw);
          acc[n] = __builtin_amdgcn_mfma_f32_16x16x32_f16(a8, b8, acc[n], 0, 0, 0);
        }
        if (needL)
          accl = __builtin_amdgcn_mfma_f32_16x16x32_f16(a8, ones8, accl, 0, 0, 0);
      }
      ++scount;
    }
  }

  _Float16* outp = pbuf + (size_t)jc * N_NODES * Ftot;
#pragma unroll
  for (int n = 0; n < NF; ++n) {
#pragma unroll
    for (int k = 0; k < 4; ++k) {
      int r = i0 + w * 16 + grp * 4 + k;
      outp[(size_t)r * Ftot + vcol + n * 16 + row_l] = (_Float16)acc[n][k];
    }
  }
  if (needL && row_l == 0) {
#pragma unroll
    for (int k = 0; k < 4; ++k)
      atomicAdd(&lsum[hN + i0 + w * 16 + grp * 4 + k], accl[k]);
  }
}

// ---------------------------------------------------------------- reduce + activation (fp16 partials)
__global__ __launch_bounds__(256) void act_kernel(float* __restrict__ dst,
                                                  const _Float16* __restrict__ pbuf,
                                                  int njc, size_t pstride,
                                                  const float* __restrict__ lsum,
                                                  int n4, int ftotShift, int fpShift, int act) {
  int idx = blockIdx.x * blockDim.x + threadIdx.x;
  if (idx >= n4) return;
  int idx4 = idx * 4;
  int r = idx4 >> ftotShift;
  int c = idx4 & ((1 << ftotShift) - 1);
  int h = c >> fpShift;
  float li = 1.0f / lsum[h * N_NODES + r];
  float vv[4] = {0, 0, 0, 0};
  for (int q = 0; q < njc; ++q) {
    half4v u = *reinterpret_cast<const half4v*>(pbuf + q * pstride + (size_t)idx4);
#pragma unroll
    for (int e = 0; e < 4; ++e) vv[e] += (float)u[e];
  }
#pragma unroll
  for (int e = 0; e < 4; ++e) {
    float x = vv[e] * li;
    x = x > 0.0f ? x : exp2f(x * LOG2E) - 1.0f;
    if (act == 1) x = 1.0f / (1.0f + exp2f(-x * LOG2E));
    vv[e] = x;
  }
  reinterpret_cast<float4*>(dst)[idx] = make_float4(vv[0], vv[1], vv[2], vv[3]);
}

// ---------------------------------------------------------------- host
extern "C" void kernel_launch(void* const* d_in, const int* in_sizes, int n_in,
                              void* d_out, int out_size, void* d_ws, size_t ws_size,
                              hipStream_t stream) {
  const float* x     = (const float*)d_in[0];
  const int*   adj   = (const int*)d_in[1];
  const float* W1    = (const float*)d_in[2];
  const float* a1    = (const float*)d_in[3];
  const float* Wo    = (const float*)d_in[4];
  const float* ao    = (const float*)d_in[5];
  const float* W2    = (const float*)d_in[6];
  const float* a2    = (const float*)d_in[7];
  const float* Wo2   = (const float*)d_in[8];
  const float* ao2   = (const float*)d_in[9];
  const float* lin_w = (const float*)d_in[10];
  const float* lin_b = (const float*)d_in[11];
  float* out = (float*)d_out;

  float* ws = (float*)d_ws;
  unsigned int* bits = (unsigned int*)ws;            // 1,179,648 u32
  float* bufA = ws + 1179648;                        // 6144*256
  float* bufB = bufA + 1572864;
  float* Bcat = bufB + 1572864;                      // 65536
  float* f1   = Bcat + 65536;                        // 24576
  float* f2   = f1 + 24576;                          // 24576
  float* lsum = f2 + 24576;                          // 24576 (contiguous: one memset zeroes f1,f2,lsum)
  float* gmaxb = lsum + 24576;                       // 16
  short* WhT  = (short*)(gmaxb + 16);                // 6144*256 fp16 bits
  short* BtW  = WhT + 1572864;                       // 384*256 bf16
  _Float16* pbuf = (_Float16*)(BtW + 98304);         // fp16 partial buffers

  const size_t PS256 = (size_t)6144 * 256;
  const size_t PS128 = (size_t)6144 * 128;

  dim3 b256(256);
  dim3 b512(512);

  bitpack_kernel<<<N_NODES, b256, 0, stream>>>(adj, bits);

  // ================= layer 1 multi-head (H=4, Fp=64), elu concat
  repack_W_kernel<<<(4 * 256 * 64 + 255) / 256, b256, 0, stream>>>(W1, Bcat, 4, 256, 64);
  transpose_w_kernel<<<dim3(8, 8), b256, 0, stream>>>(Bcat, BtW, 256, 256);
  hipMemsetAsync(f1, 0, (size_t)3 * 24576 * 4, stream);   // f1,f2,lsum
  gemm_attn_kernel<1><<<dim3(4, 96), b256, 0, stream>>>(x, BtW, a1, WhT, f1, f2, 256, 256, 64);
  gmax_kernel<<<4, b256, 0, stream>>>(f2, gmaxb);
  pv_stage_kernel<4, 4><<<dim3(1, 192, 4), b512, 0, stream>>>(f1, f2, gmaxb, bits, WhT, pbuf, lsum, 4, 64);
  act_kernel<<<dim3(1536), b256, 0, stream>>>(bufA, pbuf, 4, PS256, lsum, 6144 * 256 / 4, 8, 6, 0);

  // ================= out-attention 1 (H=1, Fp=256), sigmoid(elu)
  transpose_w_kernel<<<dim3(8, 8), b256, 0, stream>>>(Wo, BtW, 256, 256);
  hipMemsetAsync(f1, 0, (size_t)3 * 24576 * 4, stream);
  gemm_attn_kernel<1><<<dim3(4, 96), b256, 0, stream>>>(bufA, BtW, ao, WhT, f1, f2, 256, 256, 256);
  gmax_kernel<<<1, b256, 0, stream>>>(f2, gmaxb);
  pv_stage_kernel<8, 8><<<dim3(2, 384, 1), b512, 0, stream>>>(f1, f2, gmaxb, bits, WhT, pbuf, lsum, 1, 256);
  act_kernel<<<dim3(1536), b256, 0, stream>>>(bufB, pbuf, 8, PS256, lsum, 6144 * 256 / 4, 8, 8, 1);

  // ================= layer 2 multi-head (H=4, Fp=32), elu concat
  repack_W_kernel<<<(4 * 256 * 32 + 255) / 256, b256, 0, stream>>>(W2, Bcat, 4, 256, 32);
  transpose_w_kernel<<<dim3(8, 4), b256, 0, stream>>>(Bcat, BtW, 256, 128);
  hipMemsetAsync(f1, 0, (size_t)3 * 24576 * 4, stream);
  gemm_attn_kernel<2><<<dim3(2, 96), b256, 0, stream>>>(bufB, BtW, a2, WhT, f1, f2, 256, 128, 32);
  gmax_kernel<<<4, b256, 0, stream>>>(f2, gmaxb);
  pv_stage_kernel<2, 4><<<dim3(1, 192, 4), b512, 0, stream>>>(f1, f2, gmaxb, bits, WhT, pbuf, lsum, 4, 32);
  act_kernel<<<dim3(768), b256, 0, stream>>>(bufA, pbuf, 4, PS128, lsum, 6144 * 128 / 4, 7, 5, 0);

  // ================= out-attention 2 (H=1, Fp=128), sigmoid(elu)
  transpose_w_kernel<<<dim3(4, 4), b256, 0, stream>>>(Wo2, BtW, 128, 128);
  hipMemsetAsync(f1, 0, (size_t)3 * 24576 * 4, stream);
  gemm_attn_kernel<1><<<dim3(2, 96), b256, 0, stream>>>(bufA, BtW, ao2, WhT, f1, f2, 128, 128, 128);
  gmax_kernel<<<1, b256, 0, stream>>>(f2, gmaxb);
  pv_stage_kernel<8, 16><<<dim3(1, 768, 1), b512, 0, stream>>>(f1, f2, gmaxb, bits, WhT, pbuf, lsum, 1, 128);
  act_kernel<<<dim3(768), b256, 0, stream>>>(bufB, pbuf, 16, PS128, lsum, 6144 * 128 / 4, 7, 7, 1);

  // ================= final linear + relu
  transpose_w_kernel<<<dim3(4, 12), b256, 0, stream>>>(lin_w, BtW, 128, 379);
  gemm_mfma_kernel<<<dim3(6, 96), b256, 0, stream>>>(bufB, BtW, out, 128, 379, lin_b, 1);
}

// Round 24
// 279.394 us; speedup vs baseline: 1.2919x; 1.0091x over previous
//
#include <hip/hip_runtime.h>
#include <hip/hip_bf16.h>

#define N_NODES 6144
#define MASK_WORDS 192  // 6144/32
#define LOG2E 1.44269504088896f

using short8 = __attribute__((ext_vector_type(8))) short;
using s16x4  = __attribute__((ext_vector_type(4))) short;
using f32x4  = __attribute__((ext_vector_type(4))) float;
using half2v = __attribute__((ext_vector_type(2))) _Float16;
using half8v = __attribute__((ext_vector_type(8))) _Float16;
using half4v = __attribute__((ext_vector_type(4))) _Float16;
struct Half2x4 { half2v v[4]; };

// f32 -> bf16 bits, round-to-nearest-even
__device__ inline unsigned f2bf_u(float f) {
  unsigned u = __builtin_bit_cast(unsigned, f);
  u += 0x7fff + ((u >> 16) & 1);
  return u >> 16;
}
__device__ inline short f2bf(float f) { return (short)f2bf_u(f); }

// async global->LDS, 16B per lane; lds base must be wave-uniform
__device__ inline void glds16(const short* g, short* l) {
  __builtin_amdgcn_global_load_lds(
      (const __attribute__((address_space(1))) unsigned int*)g,
      (__attribute__((address_space(3))) unsigned int*)l, 16, 0, 0);
}

// ---------------------------------------------------------------- bitpack
__global__ __launch_bounds__(256) void bitpack_kernel(const int* __restrict__ adj,
                                                      unsigned int* __restrict__ bits) {
  int row = blockIdx.x;
  int wave = threadIdx.x >> 6, lane = threadIdx.x & 63;
  const int* p = adj + (long)row * N_NODES;
  for (int base = wave * 64; base < N_NODES; base += 256) {
    unsigned long long m = __ballot(p[base + lane] > 0);
    if (lane == 0) {
      bits[row * MASK_WORDS + (base >> 5)] = (unsigned int)m;
      bits[row * MASK_WORDS + (base >> 5) + 1] = (unsigned int)(m >> 32);
    }
  }
}

// ---------------------------------------------------------------- W repack
__global__ __launch_bounds__(256) void repack_W_kernel(const float* __restrict__ W,
                                                       float* __restrict__ B,
                                                       int H, int Fin, int Fp) {
  int idx = blockIdx.x * blockDim.x + threadIdx.x;
  int total = H * Fin * Fp;
  if (idx >= total) return;
  int h = idx / (Fin * Fp);
  int rem = idx - h * (Fin * Fp);
  int k = rem / Fp, c = rem - k * Fp;
  B[k * (H * Fp) + h * Fp + c] = W[idx];
}

// ---------------------------------------------------------------- weight transpose+cvt (bf16)
__global__ __launch_bounds__(256) void transpose_w_kernel(const float* __restrict__ B,
                                                          short* __restrict__ Bt,
                                                          int K, int Nc) {
  __shared__ short t[32][33];
  int k0 = blockIdx.x * 32, c0 = blockIdx.y * 32;
  int tx = threadIdx.x & 31, ty = threadIdx.x >> 5;
  for (int r = ty; r < 32; r += 8) {
    float v = (c0 + tx < Nc) ? B[(size_t)(k0 + r) * Nc + c0 + tx] : 0.0f;
    t[tx][r] = f2bf(v);
  }
  __syncthreads();
  for (int r = ty; r < 32; r += 8)
    Bt[(size_t)(c0 + r) * K + k0 + tx] = t[r][tx];
}

// ---------------------------------------------------------------- MFMA GEMM (final linear only)
__global__ __launch_bounds__(256) void gemm_mfma_kernel(const float* __restrict__ A,
                                                        const short* __restrict__ Bt,
                                                        float* __restrict__ C,
                                                        int K, int Nc,
                                                        const float* __restrict__ bias,
                                                        int act) {
  __shared__ short As[64][40];
  __shared__ short Bs[64][40];
  int m0 = blockIdx.y * 64, n0 = blockIdx.x * 64;
  int tid = threadIdx.x;
  int w = tid >> 6, l = tid & 63, row_l = l & 15, grp = l >> 4;

  f32x4 acc[4] = {f32x4{0,0,0,0}, f32x4{0,0,0,0}, f32x4{0,0,0,0}, f32x4{0,0,0,0}};

  for (int k0 = 0; k0 < K; k0 += 32) {
    __syncthreads();
#pragma unroll
    for (int s = 0; s < 2; ++s) {
      int idx = tid + s * 256;
      int r = idx >> 3, q = idx & 7;
      float4 v = *reinterpret_cast<const float4*>(&A[(size_t)(m0 + r) * K + k0 + q * 4]);
      s16x4 sv = {f2bf(v.x), f2bf(v.y), f2bf(v.z), f2bf(v.w)};
      *reinterpret_cast<s16x4*>(&As[r][q * 4]) = sv;
    }
    {
      int c = tid >> 2, kq = tid & 3;
      *reinterpret_cast<short8*>(&Bs[c][kq * 8]) =
          *reinterpret_cast<const short8*>(&Bt[(size_t)(n0 + c) * K + k0 + kq * 8]);
    }
    __syncthreads();
    short8 a = *reinterpret_cast<const short8*>(&As[w * 16 + row_l][grp * 8]);
#pragma unroll
    for (int n = 0; n < 4; ++n) {
      short8 b = *reinterpret_cast<const short8*>(&Bs[n * 16 + row_l][grp * 8]);
      acc[n] = __builtin_amdgcn_mfma_f32_16x16x32_bf16(a, b, acc[n], 0, 0, 0);
    }
  }

#pragma unroll
  for (int n = 0; n < 4; ++n) {
#pragma unroll
    for (int k = 0; k < 4; ++k) {
      int row = m0 + w * 16 + grp * 4 + k;
      int col = n0 + n * 16 + row_l;
      if (col < Nc) {
        float v = acc[n][k];
        if (bias) v += bias[col];
        if (act == 1) v = fmaxf(v, 0.0f);
        C[(size_t)row * Nc + col] = v;
      }
    }
  }
}

// ---------------------------------------------------------------- attention GEMM (fused epilogue)
template<int HPB>
__global__ __launch_bounds__(256)
void gemm_attn_kernel(const float* __restrict__ A,
                      const short* __restrict__ Bt,
                      const float* __restrict__ avec,
                      short* __restrict__ WhT,
                      float* __restrict__ f1,
                      float* __restrict__ f2,
                      int K, int Nc, int Fp) {
  __shared__ short As[64][40];
  __shared__ short Bs[64][40];
  int m0 = blockIdx.y * 64, n0 = blockIdx.x * 64;
  int tid = threadIdx.x;
  int w = tid >> 6, l = tid & 63, row_l = l & 15, grp = l >> 4;

  f32x4 acc[4] = {f32x4{0,0,0,0}, f32x4{0,0,0,0}, f32x4{0,0,0,0}, f32x4{0,0,0,0}};

  for (int k0 = 0; k0 < K; k0 += 32) {
    __syncthreads();
#pragma unroll
    for (int s = 0; s < 2; ++s) {
      int idx = tid + s * 256;
      int r = idx >> 3, q = idx & 7;
      float4 v = *reinterpret_cast<const float4*>(&A[(size_t)(m0 + r) * K + k0 + q * 4]);
      s16x4 sv = {f2bf(v.x), f2bf(v.y), f2bf(v.z), f2bf(v.w)};
      *reinterpret_cast<s16x4*>(&As[r][q * 4]) = sv;
    }
    {
      int c = tid >> 2, kq = tid & 3;
      *reinterpret_cast<short8*>(&Bs[c][kq * 8]) =
          *reinterpret_cast<const short8*>(&Bt[(size_t)(n0 + c) * K + k0 + kq * 8]);
    }
    __syncthreads();
    short8 a = *reinterpret_cast<const short8*>(&As[w * 16 + row_l][grp * 8]);
#pragma unroll
    for (int n = 0; n < 4; ++n) {
      short8 b = *reinterpret_cast<const short8*>(&Bs[n * 16 + row_l][grp * 8]);
      acc[n] = __builtin_amdgcn_mfma_f32_16x16x32_bf16(a, b, acc[n], 0, 0, 0);
    }
  }

  int baserow = m0 + w * 16 + grp * 4;

#pragma unroll
  for (int n = 0; n < 4; ++n) {
    int col = n0 + n * 16 + row_l;
    _Float16 hv[4];
#pragma unroll
    for (int k = 0; k < 4; ++k) hv[k] = (_Float16)acc[n][k];
    *reinterpret_cast<s16x4*>(&WhT[(size_t)col * N_NODES + baserow]) =
        *reinterpret_cast<s16x4*>(hv);
  }

  constexpr int NPH = 4 / HPB;
#pragma unroll
  for (int half = 0; half < HPB; ++half) {
    int col0 = n0 + half * NPH * 16;
    int h = col0 / Fp;
    float t1[4] = {0, 0, 0, 0}, t2[4] = {0, 0, 0, 0};
#pragma unroll
    for (int nn = 0; nn < NPH; ++nn) {
      int n = half * NPH + nn;
      int col = n0 + n * 16 + row_l;
      int ci = col - h * Fp;
      float av1 = avec[h * 2 * Fp + ci] * LOG2E;
      float av2 = avec[h * 2 * Fp + Fp + ci] * LOG2E;
#pragma unroll
      for (int k = 0; k < 4; ++k) {
        t1[k] += acc[n][k] * av1;
        t2[k] += acc[n][k] * av2;
      }
    }
#pragma unroll
    for (int off = 1; off < 16; off <<= 1) {
#pragma unroll
      for (int k = 0; k < 4; ++k) {
        t1[k] += __shfl_xor(t1[k], off);
        t2[k] += __shfl_xor(t2[k], off);
      }
    }
    if (row_l == 0) {
#pragma unroll
      for (int k = 0; k < 4; ++k) {
        atomicAdd(&f1[h * N_NODES + baserow + k], t1[k]);
        atomicAdd(&f2[h * N_NODES + baserow + k], t2[k]);
      }
    }
  }
}

// ---------------------------------------------------------------- per-head global max of f2
__global__ __launch_bounds__(256) void gmax_kernel(const float* __restrict__ f2s,
                                                   float* __restrict__ gmax) {
  __shared__ float red[4];
  int h = blockIdx.x;
  int tid = threadIdx.x, lane = tid & 63, w = tid >> 6;
  const float* p = f2s + h * N_NODES;
  float m = -3.0e38f;
  for (int j = tid; j < N_NODES; j += 256) m = fmaxf(m, p[j]);
  for (int off = 32; off > 0; off >>= 1) m = fmaxf(m, __shfl_xor(m, off));
  if (lane == 0) red[w] = m;
  __syncthreads();
  if (tid == 0) gmax[h] = fmaxf(fmaxf(red[0], red[1]), fmaxf(red[2], red[3]));
}

// ---------------------------------------------------------------- attention PV (fp16, fp16 partials)
// 512 threads = 8 row-strip waves (128 rows/block). P = max(Ai'E'_j, Bi'F'_j) & LUT.
// 64-j stages, triple-buffered async glds (wave-uniform base), counted vmcnt.
template<int NF, int JC>
__global__ __launch_bounds__(512)
void pv_stage_kernel(const float* __restrict__ f1s,
                     const float* __restrict__ f2s,
                     const float* __restrict__ gmax,
                     const unsigned int* __restrict__ bits,
                     const short* __restrict__ WhT,
                     _Float16* __restrict__ pbuf,
                     float* __restrict__ lsum,
                     int H, int Fp) {
  constexpr int CH = N_NODES / JC;
  constexpr int COLS = NF * 16;
  constexpr int NS = CH / 64;
  constexpr int CHUNKS = COLS * 8;           // 16B chunks per stage buffer
  constexpr int NITER = (CHUNKS + 511) / 512;
  constexpr int STEP = COLS * 64;            // shorts per buffer
  constexpr int NCH = CH / 384;
  static_assert(NCH * 384 == CH, "chunking");

  __shared__ _Float16 Esh[CH];
  __shared__ _Float16 Fsh[CH];
  __shared__ short Vt[3 * STEP];
  __shared__ uint4 Mlut[256];

  int h = blockIdx.z;
  int cb0 = blockIdx.x * COLS;
  int rb = blockIdx.y % 48;
  int jc = blockIdx.y / 48;
  int i0 = rb * 128;
  int hN = h * N_NODES, hFp = h * Fp;
  int Ftot = H * Fp;
  int tid = threadIdx.x;
  int w = tid >> 6, l = tid & 63;
  int row_l = l & 15, grp = l >> 4;

  int vcol = hFp + cb0;
  const short* Wbase = WhT + (size_t)vcol * N_NODES;
  float gm = gmax[h];

  // ---- prologue: E/F from f2, mask LUT
  {
    const float4* srcF2 = reinterpret_cast<const float4*>(f2s + hN + jc * CH);
    for (int idx = tid; idx < CH / 4; idx += 512) {
      float4 v = srcF2[idx];
      float vv[4] = {v.x, v.y, v.z, v.w};
      _Float16 e4[4], f4[4];
#pragma unroll
      for (int q = 0; q < 4; ++q) {
        float d = vv[q] - gm;
        e4[q] = (_Float16)exp2f(d);
        f4[q] = (_Float16)exp2f(0.2f * d);
      }
      *reinterpret_cast<s16x4*>(&Esh[idx * 4]) = *reinterpret_cast<s16x4*>(e4);
      *reinterpret_cast<s16x4*>(&Fsh[idx * 4]) = *reinterpret_cast<s16x4*>(f4);
    }
    if (tid < 256) {
      unsigned v = tid;
      unsigned w0 = ((v & 1u) ? 0xFFFFu : 0u) | ((v & 2u) ? 0xFFFF0000u : 0u);
      unsigned w1 = ((v & 4u) ? 0xFFFFu : 0u) | ((v & 8u) ? 0xFFFF0000u : 0u);
      unsigned w2 = ((v & 16u) ? 0xFFFFu : 0u) | ((v & 32u) ? 0xFFFF0000u : 0u);
      unsigned w3 = ((v & 64u) ? 0xFFFFu : 0u) | ((v & 128u) ? 0xFFFF0000u : 0u);
      Mlut[v] = make_uint4(w0, w1, w2, w3);
    }
  }
  __syncthreads();

  // pre-swizzled per-lane global offsets per glds iter
  size_t goff[NITER];
#pragma unroll
  for (int it = 0; it < NITER; ++it) {
    int idx = tid + it * 512;
    int c = idx >> 3, sl = idx & 7;
    int slp = sl ^ (c & 7);
    goff[it] = (size_t)(c < COLS ? c : 0) * N_NODES + jc * CH + slp * 8;
  }

  auto issue = [&](int bsel, int j0) {
#pragma unroll
    for (int it = 0; it < NITER; ++it) {
      if (it * 512 + w * 64 < CHUNKS) {
        const short* g = Wbase + goff[it] + j0;
        short* lp = &Vt[bsel * STEP + it * 4096 + w * 512];
        glds16(g, lp);
      }
    }
  };

  issue(0, 0);
  if (NS > 1) issue(1, 64);

  int i = i0 + w * 16 + row_l;
  float fi = f1s[hN + i];
  float mi = fmaxf(fi + gm, 0.2f * (fi + gm));
  _Float16 Aih = (_Float16)exp2f(fi + gm - mi);
  _Float16 Bih = (_Float16)exp2f(0.2f * (fi + gm) - mi);
  half2v Ai2 = {Aih, Aih};
  half2v Bi2 = {Bih, Bih};
  const unsigned int* mbase = bits + (size_t)i * MASK_WORDS + jc * (CH / 32);

  half8v ones8;
#pragma unroll
  for (int q = 0; q < 8; ++q) ones8[q] = (_Float16)1.0f;
  bool needL = (blockIdx.x == 0);

  f32x4 acc[NF];
#pragma unroll
  for (int n = 0; n < NF; ++n) acc[n] = f32x4{0, 0, 0, 0};
  f32x4 accl = f32x4{0, 0, 0, 0};

  int scount = 0;
#pragma unroll 1
  for (int ch = 0; ch < NCH; ++ch) {
    unsigned mw[12];
    {
      const uint4* mp = reinterpret_cast<const uint4*>(mbase + ch * 12);
#pragma unroll
      for (int q = 0; q < 3; ++q) {
        uint4 m = mp[q];
        mw[q * 4 + 0] = m.x; mw[q * 4 + 1] = m.y;
        mw[q * 4 + 2] = m.z; mw[q * 4 + 3] = m.w;
      }
    }
#pragma unroll 1
    for (int s2 = 0; s2 < 6; ++s2) {
      if (scount + 1 == NS) {
        asm volatile("s_waitcnt vmcnt(0)" ::: "memory");
      } else if (NITER == 1) {
        asm volatile("s_waitcnt vmcnt(1)" ::: "memory");
      } else {
        asm volatile("s_waitcnt vmcnt(2)" ::: "memory");
      }
      __builtin_amdgcn_sched_barrier(0);
      __builtin_amdgcn_s_barrier();
      if (scount + 2 < NS) issue((scount + 2) % 3, (scount + 2) * 64);
      const short* vb = &Vt[(scount % 3) * STEP];
#pragma unroll
      for (int hh = 0; hh < 2; ++hh) {
        unsigned wb = (mw[s2 * 2 + hh] >> (grp * 8)) & 0xffu;
        uint4 mq4 = Mlut[wb];
        unsigned mka[4] = {mq4.x, mq4.y, mq4.z, mq4.w};
        int jrel = scount * 64 + hh * 32 + grp * 8;
        half8v e8 = *reinterpret_cast<const half8v*>(&Esh[jrel]);
        half8v f8 = *reinterpret_cast<const half8v*>(&Fsh[jrel]);
        Half2x4 E2 = __builtin_bit_cast(Half2x4, e8);
        Half2x4 F2 = __builtin_bit_cast(Half2x4, f8);
        Half2x4 P2;
#pragma unroll
        for (int ep = 0; ep < 4; ++ep) {
          half2v p2 = __builtin_elementwise_max(Ai2 * E2.v[ep], Bi2 * F2.v[ep]);
          unsigned pm = __builtin_bit_cast(unsigned, p2) & mka[ep];
          P2.v[ep] = __builtin_bit_cast(half2v, pm);
        }
        half8v a8 = __builtin_bit_cast(half8v, P2);
        int j8s = ((hh << 2) | grp) ^ (row_l & 7);
#pragma unroll
        for (int n = 0; n < NF; ++n) {
          short8 braw = *reinterpret_cast<const short8*>(&vb[(n * 16 + row_l) * 64 + j8s * 8]);
          half8v b8 = __builtin_bit_cast(half8v, braw);
          acc[n] = __builtin_amdgcn_mfma_f32_16x16x32_f16(a8, b8, acc[n], 0, 0, 0);
        }
        if (needL)
          accl = __builtin_amdgcn_mfma_f32_16x16x32_f16(a8, ones8, accl, 0, 0, 0);
      }
      ++scount;
    }
  }

  _Float16* outp = pbuf + (size_t)jc * N_NODES * Ftot;
#pragma unroll
  for (int n = 0; n < NF; ++n) {
#pragma unroll
    for (int k = 0; k < 4; ++k) {
      int r = i0 + w * 16 + grp * 4 + k;
      outp[(size_t)r * Ftot + vcol + n * 16 + row_l] = (_Float16)acc[n][k];
    }
  }
  if (needL && row_l == 0) {
#pragma unroll
    for (int k = 0; k < 4; ++k)
      atomicAdd(&lsum[hN + i0 + w * 16 + grp * 4 + k], accl[k]);
  }
}

// ---------------------------------------------------------------- reduce + activation (fp16 partials)
__global__ __launch_bounds__(256) void act_kernel(float* __restrict__ dst,
                                                  const _Float16* __restrict__ pbuf,
                                                  int njc, size_t pstride,
                                                  const float* __restrict__ lsum,
                                                  int n4, int ftotShift, int fpShift, int act) {
  int idx = blockIdx.x * blockDim.x + threadIdx.x;
  if (idx >= n4) return;
  int idx4 = idx * 4;
  int r = idx4 >> ftotShift;
  int c = idx4 & ((1 << ftotShift) - 1);
  int h = c >> fpShift;
  float li = 1.0f / lsum[h * N_NODES + r];
  float vv[4] = {0, 0, 0, 0};
  for (int q = 0; q < njc; ++q) {
    half4v u = *reinterpret_cast<const half4v*>(pbuf + q * pstride + (size_t)idx4);
#pragma unroll
    for (int e = 0; e < 4; ++e) vv[e] += (float)u[e];
  }
#pragma unroll
  for (int e = 0; e < 4; ++e) {
    float x = vv[e] * li;
    x = x > 0.0f ? x : exp2f(x * LOG2E) - 1.0f;
    if (act == 1) x = 1.0f / (1.0f + exp2f(-x * LOG2E));
    vv[e] = x;
  }
  reinterpret_cast<float4*>(dst)[idx] = make_float4(vv[0], vv[1], vv[2], vv[3]);
}

// ---------------------------------------------------------------- host
extern "C" void kernel_launch(void* const* d_in, const int* in_sizes, int n_in,
                              void* d_out, int out_size, void* d_ws, size_t ws_size,
                              hipStream_t stream) {
  const float* x     = (const float*)d_in[0];
  const int*   adj   = (const int*)d_in[1];
  const float* W1    = (const float*)d_in[2];
  const float* a1    = (const float*)d_in[3];
  const float* Wo    = (const float*)d_in[4];
  const float* ao    = (const float*)d_in[5];
  const float* W2    = (const float*)d_in[6];
  const float* a2    = (const float*)d_in[7];
  const float* Wo2   = (const float*)d_in[8];
  const float* ao2   = (const float*)d_in[9];
  const float* lin_w = (const float*)d_in[10];
  const float* lin_b = (const float*)d_in[11];
  float* out = (float*)d_out;

  float* ws = (float*)d_ws;
  unsigned int* bits = (unsigned int*)ws;            // 1,179,648 u32
  float* bufA = ws + 1179648;                        // 6144*256
  float* bufB = bufA + 1572864;
  float* Bcat = bufB + 1572864;                      // 65536
  // 4 per-layer stat regions [f1 | f2 | lsum], zeroed by ONE memset at start
  float* stats = Bcat + 65536;                       // 4 * 3 * 24576
  float* gmaxb = stats + 4 * 3 * 24576;              // 16
  short* WhT  = (short*)(gmaxb + 16);                // 6144*256 fp16 bits
  short* BtW  = WhT + 1572864;                       // 384*256 bf16
  _Float16* pbuf = (_Float16*)(BtW + 98304);         // fp16 partial buffers

  const size_t PS256 = (size_t)6144 * 256;
  const size_t PS128 = (size_t)6144 * 128;
  const int SG = 3 * 24576;                          // stat group stride

  float* f1a = stats;            float* f2a = f1a + 24576; float* lsa = f2a + 24576;
  float* f1b = stats + SG;       float* f2b = f1b + 24576; float* lsb = f2b + 24576;
  float* f1c = stats + 2 * SG;   float* f2c = f1c + 24576; float* lsc = f2c + 24576;
  float* f1d = stats + 3 * SG;   float* f2d = f1d + 24576; float* lsd = f2d + 24576;

  dim3 b256(256);
  dim3 b512(512);

  hipMemsetAsync(stats, 0, (size_t)4 * SG * 4, stream);   // all f1/f2/lsum
  bitpack_kernel<<<N_NODES, b256, 0, stream>>>(adj, bits);

  // ================= layer 1 multi-head (H=4, Fp=64), elu concat
  repack_W_kernel<<<(4 * 256 * 64 + 255) / 256, b256, 0, stream>>>(W1, Bcat, 4, 256, 64);
  transpose_w_kernel<<<dim3(8, 8), b256, 0, stream>>>(Bcat, BtW, 256, 256);
  gemm_attn_kernel<1><<<dim3(4, 96), b256, 0, stream>>>(x, BtW, a1, WhT, f1a, f2a, 256, 256, 64);
  gmax_kernel<<<4, b256, 0, stream>>>(f2a, gmaxb);
  pv_stage_kernel<4, 4><<<dim3(1, 192, 4), b512, 0, stream>>>(f1a, f2a, gmaxb, bits, WhT, pbuf, lsa, 4, 64);
  act_kernel<<<dim3(1536), b256, 0, stream>>>(bufA, pbuf, 4, PS256, lsa, 6144 * 256 / 4, 8, 6, 0);

  // ================= out-attention 1 (H=1, Fp=256), sigmoid(elu)
  transpose_w_kernel<<<dim3(8, 8), b256, 0, stream>>>(Wo, BtW, 256, 256);
  gemm_attn_kernel<1><<<dim3(4, 96), b256, 0, stream>>>(bufA, BtW, ao, WhT, f1b, f2b, 256, 256, 256);
  gmax_kernel<<<1, b256, 0, stream>>>(f2b, gmaxb);
  pv_stage_kernel<8, 8><<<dim3(2, 384, 1), b512, 0, stream>>>(f1b, f2b, gmaxb, bits, WhT, pbuf, lsb, 1, 256);
  act_kernel<<<dim3(1536), b256, 0, stream>>>(bufB, pbuf, 8, PS256, lsb, 6144 * 256 / 4, 8, 8, 1);

  // ================= layer 2 multi-head (H=4, Fp=32), elu concat
  repack_W_kernel<<<(4 * 256 * 32 + 255) / 256, b256, 0, stream>>>(W2, Bcat, 4, 256, 32);
  transpose_w_kernel<<<dim3(8, 4), b256, 0, stream>>>(Bcat, BtW, 256, 128);
  gemm_attn_kernel<2><<<dim3(2, 96), b256, 0, stream>>>(bufB, BtW, a2, WhT, f1c, f2c, 256, 128, 32);
  gmax_kernel<<<4, b256, 0, stream>>>(f2c, gmaxb);
  pv_stage_kernel<2, 4><<<dim3(1, 192, 4), b512, 0, stream>>>(f1c, f2c, gmaxb, bits, WhT, pbuf, lsc, 4, 32);
  act_kernel<<<dim3(768), b256, 0, stream>>>(bufA, pbuf, 4, PS128, lsc, 6144 * 128 / 4, 7, 5, 0);

  // ================= out-attention 2 (H=1, Fp=128), sigmoid(elu)
  transpose_w_kernel<<<dim3(4, 4), b256, 0, stream>>>(Wo2, BtW, 128, 128);
  gemm_attn_kernel<1><<<dim3(2, 96), b256, 0, stream>>>(bufA, BtW, ao2, WhT, f1d, f2d, 128, 128, 128);
  gmax_kernel<<<1, b256, 0, stream>>>(f2d, gmaxb);
  pv_stage_kernel<8, 16><<<dim3(1, 768, 1), b512, 0, stream>>>(f1d, f2d, gmaxb, bits, WhT, pbuf, lsd, 1, 128);
  act_kernel<<<dim3(768), b256, 0, stream>>>(bufB, pbuf, 16, PS128, lsd, 6144 * 128 / 4, 7, 7, 1);

  // ================= final linear + relu
  transpose_w_kernel<<<dim3(4, 12), b256, 0, stream>>>(lin_w, BtW, 128, 379);
  gemm_mfma_kernel<<<dim3(6, 96), b256, 0, stream>>>(bufB, BtW, out, 128, 379, lin_b, 1);
}